// Round 1
// baseline (1011.900 us; speedup 1.0000x reference)
//
#include <hip/hip_runtime.h>
#include <cstdint>

#define NN 40000
#define EE 640000
#define GG 64

// ---------- helpers ----------
__device__ __forceinline__ float lrelu(float x) { return x > 0.f ? x : 0.2f * x; }

// order-preserving float<->uint encoding for atomicMax on signed floats
__device__ __forceinline__ unsigned fenc(float x) {
    unsigned u = __float_as_uint(x);
    return (u & 0x80000000u) ? ~u : (u | 0x80000000u);
}
__device__ __forceinline__ float fdec(unsigned e) {
    unsigned u = (e & 0x80000000u) ? (e ^ 0x80000000u) : ~e;
    return __uint_as_float(u);
}
#define ENC_NEG_INF 0x007FFFFFu   // fenc(-inf)

// ---------- CSR build ----------
__global__ void k_init(int* deg, unsigned* gmax) {
    int i = blockIdx.x * blockDim.x + threadIdx.x;
    if (i < NN) deg[i] = 0;
    if (i < GG * 64) gmax[i] = ENC_NEG_INF;
}

__global__ void k_count(const int* __restrict__ dst, int* deg) {
    int e = blockIdx.x * blockDim.x + threadIdx.x;
    if (e < EE) atomicAdd(&deg[dst[e]], 1);
}

#define SCAN_T 1024
__global__ __launch_bounds__(SCAN_T) void k_scan(const int* __restrict__ deg,
                                                 int* row_ptr, int* cursor) {
    __shared__ int part[SCAN_T];
    const int t = threadIdx.x;
    const int CH = (NN + SCAN_T - 1) / SCAN_T;   // 40
    const int base = t * CH;
    int s = 0;
    for (int j = 0; j < CH; ++j) {
        int idx = base + j;
        if (idx < NN) s += deg[idx];
    }
    part[t] = s;
    __syncthreads();
    // Hillis-Steele inclusive scan
    for (int off = 1; off < SCAN_T; off <<= 1) {
        int v = (t >= off) ? part[t - off] : 0;
        __syncthreads();
        part[t] += v;
        __syncthreads();
    }
    int run = (t == 0) ? 0 : part[t - 1];
    for (int j = 0; j < CH; ++j) {
        int idx = base + j;
        if (idx < NN) {
            row_ptr[idx] = run;
            cursor[idx]  = run;
            run += deg[idx];
        }
    }
    if (t == SCAN_T - 1) row_ptr[NN] = run;
}

__global__ void k_scatter(const int* __restrict__ src, const int* __restrict__ dst,
                          int* cursor, int* csr_src) {
    int e = blockIdx.x * blockDim.x + threadIdx.x;
    if (e < EE) {
        int p = atomicAdd(&cursor[dst[e]], 1);
        csr_src[p] = src[e];
    }
}

// ---------- f32 tiled GEMM: C[M,N] = A[M,K] @ B[K,N], all row-major ----------
// BM=BN=64, BK=32, 256 threads, 4x4 per thread. M%64==0, N%64==0, K%32==0.
__global__ __launch_bounds__(256) void gemm_f32(const float* __restrict__ A,
                                                const float* __restrict__ B,
                                                float* __restrict__ C,
                                                int M, int N, int K) {
    __shared__ float As[32][64];   // [k][m] (transposed on store)
    __shared__ float Bs[32][64];   // [k][n]
    const int tid = threadIdx.x;
    const int bm = blockIdx.x * 64;
    const int bn = blockIdx.y * 64;
    const int tx = tid & 15;
    const int ty = tid >> 4;
    float acc[4][4] = {};
    for (int k0 = 0; k0 < K; k0 += 32) {
#pragma unroll
        for (int t = 0; t < 2; ++t) {
            int f = tid + t * 256;           // 0..511 float4 slots
            int arow = f >> 3;               // 0..63
            int ac4  = f & 7;                // 0..7
            float4 a = *(const float4*)&A[(size_t)(bm + arow) * K + k0 + ac4 * 4];
            As[ac4 * 4 + 0][arow] = a.x;
            As[ac4 * 4 + 1][arow] = a.y;
            As[ac4 * 4 + 2][arow] = a.z;
            As[ac4 * 4 + 3][arow] = a.w;
            int brow = f >> 4;               // 0..31
            int bc4  = f & 15;               // 0..15
            float4 b = *(const float4*)&B[(size_t)(k0 + brow) * N + bn + bc4 * 4];
            *(float4*)&Bs[brow][bc4 * 4] = b;
        }
        __syncthreads();
#pragma unroll
        for (int kk = 0; kk < 32; ++kk) {
            float4 a4 = *(const float4*)&As[kk][ty * 4];
            float4 b4 = *(const float4*)&Bs[kk][tx * 4];
            float av[4] = {a4.x, a4.y, a4.z, a4.w};
            float bv[4] = {b4.x, b4.y, b4.z, b4.w};
#pragma unroll
            for (int i = 0; i < 4; ++i)
#pragma unroll
                for (int j = 0; j < 4; ++j)
                    acc[i][j] = fmaf(av[i], bv[j], acc[i][j]);
        }
        __syncthreads();
    }
#pragma unroll
    for (int i = 0; i < 4; ++i) {
        float4 o = {acc[i][0], acc[i][1], acc[i][2], acc[i][3]};
        *(float4*)&C[(size_t)(bm + ty * 4 + i) * N + bn + tx * 4] = o;
    }
}

// ---------- fused GATv2 edge-softmax aggregation ----------
// One wave (64 lanes) per node; lane l owns flat channels 4l..4l+3 (head = l>>4).
// Online softmax over incoming edges (+ implicit self-loop as last iteration).
// MODE 0: concat 4 heads (256 out) + bias + LeakyReLU     (layers 1, 2)
// MODE 1: mean over 4 heads (64 out) + bias, no activation (layer 3)
template <int MODE>
__global__ __launch_bounds__(256) void k_aggregate(const float* __restrict__ xl,
                                                   const float* __restrict__ xr,
                                                   const float* __restrict__ att,
                                                   const float* __restrict__ bias,
                                                   const int* __restrict__ row_ptr,
                                                   const int* __restrict__ csr_src,
                                                   float* __restrict__ out) {
    const int wave = threadIdx.x >> 6;
    const int lane = threadIdx.x & 63;
    const int node = blockIdx.x * 4 + wave;
    if (node >= NN) return;

    const float4 xri = ((const float4*)(xr + (size_t)node * 256))[lane];
    const float4 av  = ((const float4*)att)[lane];   // att flat (H*C=256) matches channels

    float m = -INFINITY, d = 0.f;
    float acc0 = 0.f, acc1 = 0.f, acc2 = 0.f, acc3 = 0.f;

    const int start = row_ptr[node];
    const int end   = row_ptr[node + 1];
    for (int e = start; e <= end; ++e) {
        const int src = (e < end) ? csr_src[e] : node;   // self-loop last
        const float4 xlv = ((const float4*)(xl + (size_t)src * 256))[lane];
        // per-lane partial of score[head] = sum_c att[h][c]*lrelu(xl+xr)
        float p = av.x * lrelu(xlv.x + xri.x)
                + av.y * lrelu(xlv.y + xri.y)
                + av.z * lrelu(xlv.z + xri.z)
                + av.w * lrelu(xlv.w + xri.w);
        p += __shfl_xor(p, 1);
        p += __shfl_xor(p, 2);
        p += __shfl_xor(p, 4);
        p += __shfl_xor(p, 8);   // 16-lane head group reduced; all lanes hold s

        const float mn    = fmaxf(m, p);
        const float scale = __expf(m - mn);   // m=-inf first iter -> 0
        const float f     = __expf(p - mn);
        d    = d * scale + f;
        acc0 = acc0 * scale + f * xlv.x;
        acc1 = acc1 * scale + f * xlv.y;
        acc2 = acc2 * scale + f * xlv.z;
        acc3 = acc3 * scale + f * xlv.w;
        m = mn;
    }

    const float inv = 1.f / (d + 1e-16f);
    if (MODE == 0) {
        const int c = lane * 4;
        float4 o;
        o.x = lrelu(acc0 * inv + bias[c + 0]);
        o.y = lrelu(acc1 * inv + bias[c + 1]);
        o.z = lrelu(acc2 * inv + bias[c + 2]);
        o.w = lrelu(acc3 * inv + bias[c + 3]);
        ((float4*)(out + (size_t)node * 256))[lane] = o;
    } else {
        float v0 = acc0 * inv, v1 = acc1 * inv, v2 = acc2 * inv, v3 = acc3 * inv;
        v0 += __shfl_xor(v0, 16); v0 += __shfl_xor(v0, 32);
        v1 += __shfl_xor(v1, 16); v1 += __shfl_xor(v1, 32);
        v2 += __shfl_xor(v2, 16); v2 += __shfl_xor(v2, 32);
        v3 += __shfl_xor(v3, 16); v3 += __shfl_xor(v3, 32);
        if (lane < 16) {
            const int c = lane * 4;
            float4 o;
            o.x = v0 * 0.25f + bias[c + 0];
            o.y = v1 * 0.25f + bias[c + 1];
            o.z = v2 * 0.25f + bias[c + 2];
            o.w = v3 * 0.25f + bias[c + 3];
            ((float4*)(out + (size_t)node * 64))[lane] = o;
        }
    }
}

// ---------- global max pool (batch is sorted) ----------
#define PNB 128
__global__ __launch_bounds__(64) void k_pool(const float* __restrict__ h3,
                                             const int* __restrict__ batch,
                                             unsigned* gmax) {
    const int lane = threadIdx.x;    // channel 0..63
    const int start = blockIdx.x * PNB;
    if (start >= NN) return;
    const int end = min(start + PNB, NN);
    int curg = batch[start];
    float best = -INFINITY;
    for (int n = start; n < end; ++n) {
        int g = batch[n];
        if (g != curg) {
            atomicMax(&gmax[curg * 64 + lane], fenc(best));
            best = -INFINITY;
            curg = g;
        }
        best = fmaxf(best, h3[(size_t)n * 64 + lane]);
    }
    atomicMax(&gmax[curg * 64 + lane], fenc(best));
}

__global__ void k_decode(const unsigned* __restrict__ gmax, float* __restrict__ outg) {
    int i = blockIdx.x * blockDim.x + threadIdx.x;
    if (i < GG * 64) outg[i] = fdec(gmax[i]);
}

__global__ __launch_bounds__(128) void k_head(const float* __restrict__ g,
                                              const float* __restrict__ Wc,
                                              const float* __restrict__ bc,
                                              float* __restrict__ logits) {
    const int t = threadIdx.x;          // 0..127
    const int gr = t >> 1, o = t & 1;
    float s = bc[o];
    for (int c = 0; c < 64; ++c) s = fmaf(g[gr * 64 + c], Wc[c * 2 + o], s);
    logits[t] = s;
}

// ---------- launch ----------
extern "C" void kernel_launch(void* const* d_in, const int* in_sizes, int n_in,
                              void* d_out, int out_size, void* d_ws, size_t ws_size,
                              hipStream_t stream) {
    const float* x     = (const float*)d_in[0];
    const int*   ei    = (const int*)d_in[1];
    const int*   batch = (const int*)d_in[2];
    const float* Wl1 = (const float*)d_in[3];
    const float* Wr1 = (const float*)d_in[4];
    const float* att1 = (const float*)d_in[5];
    const float* b1  = (const float*)d_in[6];
    const float* Wl2 = (const float*)d_in[7];
    const float* Wr2 = (const float*)d_in[8];
    const float* att2 = (const float*)d_in[9];
    const float* b2  = (const float*)d_in[10];
    const float* Wl3 = (const float*)d_in[11];
    const float* Wr3 = (const float*)d_in[12];
    const float* att3 = (const float*)d_in[13];
    const float* b3  = (const float*)d_in[14];
    const float* Wc  = (const float*)d_in[15];
    const float* bc  = (const float*)d_in[16];
    float* out = (float*)d_out;   // [0..127]=logits, [128..4223]=g

    char* ws = (char*)d_ws;
    size_t off = 0;
    auto alloc = [&](size_t bytes) -> void* {
        void* p = ws + off;
        off += (bytes + 255) & ~(size_t)255;
        return p;
    };
    float* xl      = (float*)alloc((size_t)NN * 256 * 4);
    float* xr      = (float*)alloc((size_t)NN * 256 * 4);
    float* H       = (float*)alloc((size_t)NN * 256 * 4);
    float* h3      = (float*)alloc((size_t)NN * 64 * 4);
    int*   deg     = (int*)alloc((size_t)NN * 4);
    int*   cursor  = (int*)alloc((size_t)NN * 4);
    int*   row_ptr = (int*)alloc((size_t)(NN + 1) * 4);
    int*   csr_src = (int*)alloc((size_t)EE * 4);
    unsigned* gmax = (unsigned*)alloc((size_t)GG * 64 * 4);
    if (off > ws_size) return;   // workspace too small; bail

    const int* esrc = ei;
    const int* edst = ei + EE;

    // CSR build (graph is identical for all 3 layers)
    k_init<<<(NN + 255) / 256, 256, 0, stream>>>(deg, gmax);
    k_count<<<(EE + 255) / 256, 256, 0, stream>>>(edst, deg);
    k_scan<<<1, SCAN_T, 0, stream>>>(deg, row_ptr, cursor);
    k_scatter<<<(EE + 255) / 256, 256, 0, stream>>>(esrc, edst, cursor, csr_src);

    const dim3 gemm_grid(NN / 64, 256 / 64);   // 625 x 4
    const int agg_blocks = NN / 4;             // 10000, 4 waves/block

    // Layer 1 (K=128)
    gemm_f32<<<gemm_grid, 256, 0, stream>>>(x, Wl1, xl, NN, 256, 128);
    gemm_f32<<<gemm_grid, 256, 0, stream>>>(x, Wr1, xr, NN, 256, 128);
    k_aggregate<0><<<agg_blocks, 256, 0, stream>>>(xl, xr, att1, b1, row_ptr, csr_src, H);
    // Layer 2 (K=256)
    gemm_f32<<<gemm_grid, 256, 0, stream>>>(H, Wl2, xl, NN, 256, 256);
    gemm_f32<<<gemm_grid, 256, 0, stream>>>(H, Wr2, xr, NN, 256, 256);
    k_aggregate<0><<<agg_blocks, 256, 0, stream>>>(xl, xr, att2, b2, row_ptr, csr_src, H);
    // Layer 3 (K=256), mean over heads
    gemm_f32<<<gemm_grid, 256, 0, stream>>>(H, Wl3, xl, NN, 256, 256);
    gemm_f32<<<gemm_grid, 256, 0, stream>>>(H, Wr3, xr, NN, 256, 256);
    k_aggregate<1><<<agg_blocks, 256, 0, stream>>>(xl, xr, att3, b3, row_ptr, csr_src, h3);

    // Pool + head
    k_pool<<<(NN + PNB - 1) / PNB, 64, 0, stream>>>(h3, batch, gmax);
    k_decode<<<(GG * 64 + 255) / 256, 256, 0, stream>>>(gmax, out + 128);
    k_head<<<1, 128, 0, stream>>>(out + 128, Wc, bc, out);
}

// Round 3
// 956.542 us; speedup vs baseline: 1.0579x; 1.0579x over previous
//
#include <hip/hip_runtime.h>
#include <cstdint>

#define NN 40000
#define EE 640000
#define GG 64

// ---------- helpers ----------
__device__ __forceinline__ float lrelu(float x) { return x > 0.f ? x : 0.2f * x; }

// order-preserving float<->uint encoding for atomicMax on signed floats
__device__ __forceinline__ unsigned fenc(float x) {
    unsigned u = __float_as_uint(x);
    return (u & 0x80000000u) ? ~u : (u | 0x80000000u);
}
__device__ __forceinline__ float fdec(unsigned e) {
    unsigned u = (e & 0x80000000u) ? (e ^ 0x80000000u) : ~e;
    return __uint_as_float(u);
}
#define ENC_NEG_INF 0x007FFFFFu   // fenc(-inf)

// ---------- CSR build ----------
__global__ void k_init(int* deg, unsigned* gmax) {
    int i = blockIdx.x * blockDim.x + threadIdx.x;
    if (i < NN) deg[i] = 0;
    if (i < GG * 64) gmax[i] = ENC_NEG_INF;
}

__global__ void k_count(const int* __restrict__ dst, int* deg) {
    int e = blockIdx.x * blockDim.x + threadIdx.x;
    if (e < EE) atomicAdd(&deg[dst[e]], 1);
}

#define SCAN_T 1024
__global__ __launch_bounds__(SCAN_T) void k_scan(const int* __restrict__ deg,
                                                 int* row_ptr, int* cursor) {
    __shared__ int part[SCAN_T];
    const int t = threadIdx.x;
    const int CH = (NN + SCAN_T - 1) / SCAN_T;   // 40
    const int base = t * CH;
    int s = 0;
    for (int j = 0; j < CH; ++j) {
        int idx = base + j;
        if (idx < NN) s += deg[idx];
    }
    part[t] = s;
    __syncthreads();
    // Hillis-Steele inclusive scan
    for (int off = 1; off < SCAN_T; off <<= 1) {
        int v = (t >= off) ? part[t - off] : 0;
        __syncthreads();
        part[t] += v;
        __syncthreads();
    }
    int run = (t == 0) ? 0 : part[t - 1];
    for (int j = 0; j < CH; ++j) {
        int idx = base + j;
        if (idx < NN) {
            row_ptr[idx] = run;
            cursor[idx]  = run;
            run += deg[idx];
        }
    }
    if (t == SCAN_T - 1) row_ptr[NN] = run;
}

__global__ void k_scatter(const int* __restrict__ src, const int* __restrict__ dst,
                          int* cursor, int* csr_src) {
    int e = blockIdx.x * blockDim.x + threadIdx.x;
    if (e < EE) {
        int p = atomicAdd(&cursor[dst[e]], 1);
        csr_src[p] = src[e];
    }
}

// ---------- f32 tiled GEMM: C[M,N] = A[M,K] @ B[K,N], row-major ----------
// BM=BN=128, BK=32, 256 threads, 8x8 per thread. N%128==0, K%32==0; M guarded.
#define TBM 128
#define TBN 128
#define TBK 32
__global__ __launch_bounds__(256) void gemm_f32(const float* __restrict__ A,
                                                const float* __restrict__ B,
                                                float* __restrict__ C,
                                                int M, int N, int K) {
    __shared__ float As[TBK][TBM + 2];   // [k][m], +2 pad: stores 2-way (free), float2-aligned reads
    __shared__ float Bs[TBK][TBN];       // [k][n]
    const int tid = threadIdx.x;
    const int bm = blockIdx.x * TBM;
    const int bn = blockIdx.y * TBN;
    const int tx = tid & 15;         // col group
    const int ty = tid >> 4;         // row group
    float acc[8][8] = {};
    for (int k0 = 0; k0 < K; k0 += TBK) {
#pragma unroll
        for (int t = 0; t < 4; ++t) {
            int s = tid + t * 256;            // 0..1023 float4 slots
            int arow = s >> 3;                // 0..127
            int ak = (s & 7) * 4;             // 0..28
            int grow = bm + arow; if (grow >= M) grow = M - 1;
            float4 a = *(const float4*)&A[(size_t)grow * K + k0 + ak];
            As[ak + 0][arow] = a.x;
            As[ak + 1][arow] = a.y;
            As[ak + 2][arow] = a.z;
            As[ak + 3][arow] = a.w;
            int brow = s >> 5;                // 0..31
            int bc = (s & 31) * 4;            // 0..124
            *(float4*)&Bs[brow][bc] = *(const float4*)&B[(size_t)(k0 + brow) * N + bn + bc];
        }
        __syncthreads();
#pragma unroll
        for (int kk = 0; kk < TBK; ++kk) {
            float a[8], b[8];
            *(float2*)&a[0] = *(const float2*)&As[kk][ty * 8 + 0];
            *(float2*)&a[2] = *(const float2*)&As[kk][ty * 8 + 2];
            *(float2*)&a[4] = *(const float2*)&As[kk][ty * 8 + 4];
            *(float2*)&a[6] = *(const float2*)&As[kk][ty * 8 + 6];
            *(float4*)&b[0] = *(const float4*)&Bs[kk][tx * 8];
            *(float4*)&b[4] = *(const float4*)&Bs[kk][tx * 8 + 4];
#pragma unroll
            for (int i = 0; i < 8; ++i)
#pragma unroll
                for (int j = 0; j < 8; ++j)
                    acc[i][j] = fmaf(a[i], b[j], acc[i][j]);
        }
        __syncthreads();
    }
#pragma unroll
    for (int i = 0; i < 8; ++i) {
        int grow = bm + ty * 8 + i;
        if (grow < M) {
            *(float4*)&C[(size_t)grow * N + bn + tx * 8]     = *(float4*)&acc[i][0];
            *(float4*)&C[(size_t)grow * N + bn + tx * 8 + 4] = *(float4*)&acc[i][4];
        }
    }
}

// ---------- fused GATv2 edge-softmax aggregation ----------
// One wave per node; lane l owns flat channels 4l..4l+3 (head = l>>4).
// Online softmax over incoming edges (+ self-loop as final virtual edge).
// 2-edge unrolled: two gathers in flight per iteration, merged softmax update.
// MODE 0: concat 4 heads (256 out) + bias + LeakyReLU     (layers 1, 2)
// MODE 1: mean over 4 heads (64 out) + bias, no activation (layer 3)
template <int MODE>
__global__ __launch_bounds__(256) void k_aggregate(const float* __restrict__ xl,
                                                   const float* __restrict__ xr,
                                                   const float* __restrict__ att,
                                                   const float* __restrict__ bias,
                                                   const int* __restrict__ row_ptr,
                                                   const int* __restrict__ csr_src,
                                                   float* __restrict__ out) {
    const int wave = threadIdx.x >> 6;
    const int lane = threadIdx.x & 63;
    const int node = blockIdx.x * 4 + wave;
    if (node >= NN) return;

    const float4 xri = ((const float4*)(xr + (size_t)node * 256))[lane];
    const float4 av  = ((const float4*)att)[lane];   // att flat (H*C=256) matches channels

    float m = -INFINITY, d = 0.f;
    float acc0 = 0.f, acc1 = 0.f, acc2 = 0.f, acc3 = 0.f;

    const int start = row_ptr[node];
    const int end   = row_ptr[node + 1];
    const int L = end - start + 1;   // + self-loop as last virtual edge

    int i = 0;
    for (; i + 1 < L; i += 2) {
        const int ea = start + i, eb = start + i + 1;
        const int sa = (ea < end) ? csr_src[ea] : node;
        const int sb = (eb < end) ? csr_src[eb] : node;
        const float4 xa = ((const float4*)(xl + (size_t)sa * 256))[lane];
        const float4 xb = ((const float4*)(xl + (size_t)sb * 256))[lane];
        float pa = av.x * lrelu(xa.x + xri.x) + av.y * lrelu(xa.y + xri.y)
                 + av.z * lrelu(xa.z + xri.z) + av.w * lrelu(xa.w + xri.w);
        float pb = av.x * lrelu(xb.x + xri.x) + av.y * lrelu(xb.y + xri.y)
                 + av.z * lrelu(xb.z + xri.z) + av.w * lrelu(xb.w + xri.w);
        pa += __shfl_xor(pa, 1); pb += __shfl_xor(pb, 1);
        pa += __shfl_xor(pa, 2); pb += __shfl_xor(pb, 2);
        pa += __shfl_xor(pa, 4); pb += __shfl_xor(pb, 4);
        pa += __shfl_xor(pa, 8); pb += __shfl_xor(pb, 8);

        const float mn    = fmaxf(m, fmaxf(pa, pb));
        const float scale = __expf(m - mn);     // m=-inf first iter -> 0
        const float fa    = __expf(pa - mn);
        const float fb    = __expf(pb - mn);
        d    = d * scale + fa + fb;
        acc0 = acc0 * scale + fa * xa.x + fb * xb.x;
        acc1 = acc1 * scale + fa * xa.y + fb * xb.y;
        acc2 = acc2 * scale + fa * xa.z + fb * xb.z;
        acc3 = acc3 * scale + fa * xa.w + fb * xb.w;
        m = mn;
    }
    if (i < L) {   // tail: single edge or the self-loop
        const int ea = start + i;
        const int sa = (ea < end) ? csr_src[ea] : node;
        const float4 xa = ((const float4*)(xl + (size_t)sa * 256))[lane];
        float pa = av.x * lrelu(xa.x + xri.x) + av.y * lrelu(xa.y + xri.y)
                 + av.z * lrelu(xa.z + xri.z) + av.w * lrelu(xa.w + xri.w);
        pa += __shfl_xor(pa, 1);
        pa += __shfl_xor(pa, 2);
        pa += __shfl_xor(pa, 4);
        pa += __shfl_xor(pa, 8);
        const float mn    = fmaxf(m, pa);
        const float scale = __expf(m - mn);
        const float fa    = __expf(pa - mn);
        d    = d * scale + fa;
        acc0 = acc0 * scale + fa * xa.x;
        acc1 = acc1 * scale + fa * xa.y;
        acc2 = acc2 * scale + fa * xa.z;
        acc3 = acc3 * scale + fa * xa.w;
        m = mn;
    }

    const float inv = 1.f / (d + 1e-16f);
    if (MODE == 0) {
        const int c = lane * 4;
        float4 o;
        o.x = lrelu(acc0 * inv + bias[c + 0]);
        o.y = lrelu(acc1 * inv + bias[c + 1]);
        o.z = lrelu(acc2 * inv + bias[c + 2]);
        o.w = lrelu(acc3 * inv + bias[c + 3]);
        ((float4*)(out + (size_t)node * 256))[lane] = o;
    } else {
        float v0 = acc0 * inv, v1 = acc1 * inv, v2 = acc2 * inv, v3 = acc3 * inv;
        v0 += __shfl_xor(v0, 16); v0 += __shfl_xor(v0, 32);
        v1 += __shfl_xor(v1, 16); v1 += __shfl_xor(v1, 32);
        v2 += __shfl_xor(v2, 16); v2 += __shfl_xor(v2, 32);
        v3 += __shfl_xor(v3, 16); v3 += __shfl_xor(v3, 32);
        if (lane < 16) {
            const int c = lane * 4;
            float4 o;
            o.x = v0 * 0.25f + bias[c + 0];
            o.y = v1 * 0.25f + bias[c + 1];
            o.z = v2 * 0.25f + bias[c + 2];
            o.w = v3 * 0.25f + bias[c + 3];
            ((float4*)(out + (size_t)node * 64))[lane] = o;
        }
    }
}

// ---------- global max pool (batch is sorted) ----------
#define PNB 32
__global__ __launch_bounds__(64) void k_pool(const float* __restrict__ h3,
                                             const int* __restrict__ batch,
                                             unsigned* gmax) {
    const int lane = threadIdx.x;    // channel 0..63
    const int start = blockIdx.x * PNB;
    if (start >= NN) return;
    const int end = min(start + PNB, NN);
    int curg = batch[start];
    float best = -INFINITY;
    for (int n = start; n < end; ++n) {
        int g = batch[n];
        if (g != curg) {
            atomicMax(&gmax[curg * 64 + lane], fenc(best));
            best = -INFINITY;
            curg = g;
        }
        best = fmaxf(best, h3[(size_t)n * 64 + lane]);
    }
    atomicMax(&gmax[curg * 64 + lane], fenc(best));
}

__global__ void k_decode(const unsigned* __restrict__ gmax, float* __restrict__ outg) {
    int i = blockIdx.x * blockDim.x + threadIdx.x;
    if (i < GG * 64) outg[i] = fdec(gmax[i]);
}

__global__ __launch_bounds__(128) void k_head(const float* __restrict__ g,
                                              const float* __restrict__ Wc,
                                              const float* __restrict__ bc,
                                              float* __restrict__ logits) {
    const int t = threadIdx.x;          // 0..127
    const int gr = t >> 1, o = t & 1;
    float s = bc[o];
    for (int c = 0; c < 64; ++c) s = fmaf(g[gr * 64 + c], Wc[c * 2 + o], s);
    logits[t] = s;
}

// ---------- launch ----------
extern "C" void kernel_launch(void* const* d_in, const int* in_sizes, int n_in,
                              void* d_out, int out_size, void* d_ws, size_t ws_size,
                              hipStream_t stream) {
    const float* x     = (const float*)d_in[0];
    const int*   ei    = (const int*)d_in[1];
    const int*   batch = (const int*)d_in[2];
    const float* Wl1 = (const float*)d_in[3];
    const float* Wr1 = (const float*)d_in[4];
    const float* att1 = (const float*)d_in[5];
    const float* b1  = (const float*)d_in[6];
    const float* Wl2 = (const float*)d_in[7];
    const float* Wr2 = (const float*)d_in[8];
    const float* att2 = (const float*)d_in[9];
    const float* b2  = (const float*)d_in[10];
    const float* Wl3 = (const float*)d_in[11];
    const float* Wr3 = (const float*)d_in[12];
    const float* att3 = (const float*)d_in[13];
    const float* b3  = (const float*)d_in[14];
    const float* Wc  = (const float*)d_in[15];
    const float* bc  = (const float*)d_in[16];
    float* out = (float*)d_out;   // [0..127]=logits, [128..4223]=g

    char* ws = (char*)d_ws;
    size_t off = 0;
    auto alloc = [&](size_t bytes) -> void* {
        void* p = ws + off;
        off += (bytes + 255) & ~(size_t)255;
        return p;
    };
    float* xl      = (float*)alloc((size_t)NN * 256 * 4);
    float* xr      = (float*)alloc((size_t)NN * 256 * 4);
    float* H       = (float*)alloc((size_t)NN * 256 * 4);
    float* h3      = (float*)alloc((size_t)NN * 64 * 4);
    int*   deg     = (int*)alloc((size_t)NN * 4);
    int*   cursor  = (int*)alloc((size_t)NN * 4);
    int*   row_ptr = (int*)alloc((size_t)(NN + 1) * 4);
    int*   csr_src = (int*)alloc((size_t)EE * 4);
    unsigned* gmax = (unsigned*)alloc((size_t)GG * 64 * 4);
    if (off > ws_size) return;   // workspace too small; bail

    const int* esrc = ei;
    const int* edst = ei + EE;

    // CSR build (graph is identical for all 3 layers)
    k_init<<<(NN + 255) / 256, 256, 0, stream>>>(deg, gmax);
    k_count<<<(EE + 255) / 256, 256, 0, stream>>>(edst, deg);
    k_scan<<<1, SCAN_T, 0, stream>>>(deg, row_ptr, cursor);
    k_scatter<<<(EE + 255) / 256, 256, 0, stream>>>(esrc, edst, cursor, csr_src);

    const dim3 gemm_grid((NN + TBM - 1) / TBM, 256 / TBN);   // 313 x 2
    const int agg_blocks = NN / 4;                           // 10000, 4 waves/block

    // Layer 1 (K=128)
    gemm_f32<<<gemm_grid, 256, 0, stream>>>(x, Wl1, xl, NN, 256, 128);
    gemm_f32<<<gemm_grid, 256, 0, stream>>>(x, Wr1, xr, NN, 256, 128);
    k_aggregate<0><<<agg_blocks, 256, 0, stream>>>(xl, xr, att1, b1, row_ptr, csr_src, H);
    // Layer 2 (K=256)
    gemm_f32<<<gemm_grid, 256, 0, stream>>>(H, Wl2, xl, NN, 256, 256);
    gemm_f32<<<gemm_grid, 256, 0, stream>>>(H, Wr2, xr, NN, 256, 256);
    k_aggregate<0><<<agg_blocks, 256, 0, stream>>>(xl, xr, att2, b2, row_ptr, csr_src, H);
    // Layer 3 (K=256), mean over heads
    gemm_f32<<<gemm_grid, 256, 0, stream>>>(H, Wl3, xl, NN, 256, 256);
    gemm_f32<<<gemm_grid, 256, 0, stream>>>(H, Wr3, xr, NN, 256, 256);
    k_aggregate<1><<<agg_blocks, 256, 0, stream>>>(xl, xr, att3, b3, row_ptr, csr_src, h3);

    // Pool + head
    k_pool<<<(NN + PNB - 1) / PNB, 64, 0, stream>>>(h3, batch, gmax);
    k_decode<<<(GG * 64 + 255) / 256, 256, 0, stream>>>(gmax, out + 128);
    k_head<<<1, 128, 0, stream>>>(out + 128, Wc, bc, out);
}

// Round 4
// 805.932 us; speedup vs baseline: 1.2556x; 1.1869x over previous
//
#include <hip/hip_runtime.h>
#include <cstdint>

#define NN 40000
#define EE 640000
#define GG 64

typedef short bf16x8 __attribute__((ext_vector_type(8)));
typedef float f32x4 __attribute__((ext_vector_type(4)));

// ---------- helpers ----------
__device__ __forceinline__ float lrelu(float x) { return x > 0.f ? x : 0.2f * x; }

// f32 -> bf16 (RNE) and back, via bit ops (no reliance on __bf16 scalar support)
__device__ __forceinline__ unsigned short f2bf(float f) {
    unsigned u = __float_as_uint(f);
    return (unsigned short)((u + 0x7FFFu + ((u >> 16) & 1u)) >> 16);
}
__device__ __forceinline__ float bf2f(unsigned short h) {
    return __uint_as_float(((unsigned)h) << 16);
}

// order-preserving float<->uint encoding for atomicMax on signed floats
__device__ __forceinline__ unsigned fenc(float x) {
    unsigned u = __float_as_uint(x);
    return (u & 0x80000000u) ? ~u : (u | 0x80000000u);
}
__device__ __forceinline__ float fdec(unsigned e) {
    unsigned u = (e & 0x80000000u) ? (e ^ 0x80000000u) : ~e;
    return __uint_as_float(u);
}
#define ENC_NEG_INF 0x007FFFFFu   // fenc(-inf)

// ---------- CSR build ----------
__global__ void k_init(int* deg, unsigned* gmax) {
    int i = blockIdx.x * blockDim.x + threadIdx.x;
    if (i < NN) deg[i] = 0;
    if (i < GG * 64) gmax[i] = ENC_NEG_INF;
}

__global__ void k_count(const int* __restrict__ dst, int* deg) {
    int e = blockIdx.x * blockDim.x + threadIdx.x;
    if (e < EE) atomicAdd(&deg[dst[e]], 1);
}

#define SCAN_T 1024
__global__ __launch_bounds__(SCAN_T) void k_scan(const int* __restrict__ deg,
                                                 int* row_ptr, int* cursor) {
    __shared__ int part[SCAN_T];
    const int t = threadIdx.x;
    const int CH = (NN + SCAN_T - 1) / SCAN_T;   // 40
    const int base = t * CH;
    int s = 0;
    for (int j = 0; j < CH; ++j) {
        int idx = base + j;
        if (idx < NN) s += deg[idx];
    }
    part[t] = s;
    __syncthreads();
    for (int off = 1; off < SCAN_T; off <<= 1) {
        int v = (t >= off) ? part[t - off] : 0;
        __syncthreads();
        part[t] += v;
        __syncthreads();
    }
    int run = (t == 0) ? 0 : part[t - 1];
    for (int j = 0; j < CH; ++j) {
        int idx = base + j;
        if (idx < NN) {
            row_ptr[idx] = run;
            cursor[idx]  = run;
            run += deg[idx];
        }
    }
    if (t == SCAN_T - 1) row_ptr[NN] = run;
}

__global__ void k_scatter(const int* __restrict__ src, const int* __restrict__ dst,
                          int* cursor, int* csr_src) {
    int e = blockIdx.x * blockDim.x + threadIdx.x;
    if (e < EE) {
        int p = atomicAdd(&cursor[dst[e]], 1);
        csr_src[p] = src[e];
    }
}

// ---------- bf16x3 split of a dense f32 array (x -> Ah/Am/Al), vectorized ----------
__global__ void k_xsplit(const float* __restrict__ x,
                         ushort* __restrict__ ah, ushort* __restrict__ am,
                         ushort* __restrict__ al, int total4) {
    int i = blockIdx.x * blockDim.x + threadIdx.x;
    if (i >= total4) return;
    float4 v = ((const float4*)x)[i];
    ushort4 H, M, L;
    float* pv = &v.x;
    unsigned short* pH = &H.x; unsigned short* pM = &M.x; unsigned short* pL = &L.x;
#pragma unroll
    for (int j = 0; j < 4; ++j) {
        float a = pv[j];
        unsigned short h = f2bf(a);
        float r1 = a - bf2f(h);
        unsigned short m = f2bf(r1);
        float r2 = r1 - bf2f(m);
        unsigned short l = f2bf(r2);
        pH[j] = h; pM[j] = m; pL[j] = l;
    }
    ((ushort4*)ah)[i] = H;
    ((ushort4*)am)[i] = M;
    ((ushort4*)al)[i] = L;
}

// ---------- transpose + bf16x3 split of weight: W[K][256] f32 -> Wt{h,m,l}[256][K] bf16 ----------
__global__ __launch_bounds__(256) void k_wsplit(const float* __restrict__ W, int K,
                                                ushort* __restrict__ th,
                                                ushort* __restrict__ tm,
                                                ushort* __restrict__ tl) {
    __shared__ float t[32][33];
    const int n0 = blockIdx.x * 32;   // N=256 fixed
    const int k0 = blockIdx.y * 32;
    const int tx = threadIdx.x;       // 0..31
    const int ty = threadIdx.y;       // 0..7
#pragma unroll
    for (int i = 0; i < 4; ++i) {
        int kl = ty * 4 + i;
        t[kl][tx] = W[(size_t)(k0 + kl) * 256 + n0 + tx];
    }
    __syncthreads();
#pragma unroll
    for (int i = 0; i < 4; ++i) {
        int nl = ty * 4 + i;
        float a = t[tx][nl];
        unsigned short h = f2bf(a);
        float r1 = a - bf2f(h);
        unsigned short m = f2bf(r1);
        float r2 = r1 - bf2f(m);
        unsigned short l = f2bf(r2);
        size_t o = (size_t)(n0 + nl) * K + k0 + tx;
        th[o] = h; tm[o] = m; tl[o] = l;
    }
}

// ---------- bf16x3-split MFMA GEMM: C[M][256] = A[M][K] @ B[K][256] ----------
// A given as 3 bf16 planes [M][K]; B given as 3 bf16 planes TRANSPOSED [256][K].
// 128x128 block tile, BK=32, 4 waves of 64x64, 16x16x32 MFMA, 6 split products.
#define GBM 128
#define GBK 32
__global__ __launch_bounds__(256, 2) void gemm3(const ushort* __restrict__ Ah,
                                                const ushort* __restrict__ Am,
                                                const ushort* __restrict__ Al,
                                                const ushort* __restrict__ Bh,
                                                const ushort* __restrict__ Bm,
                                                const ushort* __restrict__ Bl,
                                                float* __restrict__ C,
                                                int M, int K) {
    __shared__ ushort sA[3][GBM * GBK];   // [row][chunk-swizzled k], row=64B
    __shared__ ushort sB[3][GBM * GBK];   // [n][chunk-swizzled k]
    const int tid  = threadIdx.x;
    const int lane = tid & 63;
    const int wv   = tid >> 6;
    const int wm   = wv & 1;              // wave row 0..1
    const int wn   = wv >> 1;             // wave col 0..1
    const int bm   = blockIdx.x * GBM;
    const int bn   = blockIdx.y * 128;

    f32x4 acc[4][4];
#pragma unroll
    for (int i = 0; i < 4; ++i)
#pragma unroll
        for (int j = 0; j < 4; ++j)
            acc[i][j] = (f32x4){0.f, 0.f, 0.f, 0.f};

    const ushort* Aarr[3] = {Ah, Am, Al};
    const ushort* Barr[3] = {Bh, Bm, Bl};

    for (int k0 = 0; k0 < K; k0 += GBK) {
        // stage 6 tiles: 512 16B-chunks per tile, 2 per thread
#pragma unroll
        for (int qq = 0; qq < 2; ++qq) {
            const int q   = tid + qq * 256;
            const int row = q >> 2;                 // 0..127
            const int c   = q & 3;                  // real chunk
            const int cs  = c ^ ((row >> 1) & 3);   // swizzled slot
            const int lidx = row * 32 + cs * 8;     // ushort index (16B aligned)
            int ga = bm + row; if (ga >= M) ga = M - 1;
            const size_t aoff = (size_t)ga * K + k0 + c * 8;
            const size_t boff = (size_t)(bn + row) * K + k0 + c * 8;
#pragma unroll
            for (int s = 0; s < 3; ++s) {
                *(uint4*)&sA[s][lidx] = *(const uint4*)&Aarr[s][aoff];
                *(uint4*)&sB[s][lidx] = *(const uint4*)&Barr[s][boff];
            }
        }
        __syncthreads();

        // fragments: lane l -> A row = (l&15), k chunk = (l>>4)
        bf16x8 a[3][4], b[3][4];
        const int fc = lane >> 4;       // 0..3
        const int fr = lane & 15;
#pragma unroll
        for (int mi = 0; mi < 4; ++mi) {
            const int row = wm * 64 + mi * 16 + fr;
            const int cs  = fc ^ ((row >> 1) & 3);
            const int idx = row * 32 + cs * 8;
#pragma unroll
            for (int s = 0; s < 3; ++s)
                a[s][mi] = *(const bf16x8*)&sA[s][idx];
        }
#pragma unroll
        for (int ni = 0; ni < 4; ++ni) {
            const int row = wn * 64 + ni * 16 + fr;
            const int cs  = fc ^ ((row >> 1) & 3);
            const int idx = row * 32 + cs * 8;
#pragma unroll
            for (int s = 0; s < 3; ++s)
                b[s][ni] = *(const bf16x8*)&sB[s][idx];
        }

#pragma unroll
        for (int mi = 0; mi < 4; ++mi)
#pragma unroll
            for (int ni = 0; ni < 4; ++ni) {
                f32x4 c0 = acc[mi][ni];
                c0 = __builtin_amdgcn_mfma_f32_16x16x32_bf16(a[0][mi], b[0][ni], c0, 0, 0, 0);
                c0 = __builtin_amdgcn_mfma_f32_16x16x32_bf16(a[0][mi], b[1][ni], c0, 0, 0, 0);
                c0 = __builtin_amdgcn_mfma_f32_16x16x32_bf16(a[1][mi], b[0][ni], c0, 0, 0, 0);
                c0 = __builtin_amdgcn_mfma_f32_16x16x32_bf16(a[0][mi], b[2][ni], c0, 0, 0, 0);
                c0 = __builtin_amdgcn_mfma_f32_16x16x32_bf16(a[2][mi], b[0][ni], c0, 0, 0, 0);
                c0 = __builtin_amdgcn_mfma_f32_16x16x32_bf16(a[1][mi], b[1][ni], c0, 0, 0, 0);
                acc[mi][ni] = c0;
            }
        __syncthreads();
    }

    // epilogue: C/D layout col=lane&15, row=(lane>>4)*4+reg
#pragma unroll
    for (int mi = 0; mi < 4; ++mi) {
#pragma unroll
        for (int r = 0; r < 4; ++r) {
            const int row = bm + wm * 64 + mi * 16 + (lane >> 4) * 4 + r;
            if (row < M) {
#pragma unroll
                for (int ni = 0; ni < 4; ++ni) {
                    const int col = bn + wn * 64 + ni * 16 + (lane & 15);
                    C[(size_t)row * 256 + col] = acc[mi][ni][r];
                }
            }
        }
    }
}

// ---------- fused GATv2 edge-softmax aggregation ----------
// One wave per node; lane l owns flat channels 4l..4l+3 (head = l>>4).
// MODE 0: concat 4 heads + bias + LeakyReLU, output as bf16x3 split (feeds next GEMM)
// MODE 1: mean over 4 heads (64 out) + bias, f32 output (feeds pool)
template <int MODE>
__global__ __launch_bounds__(256) void k_aggregate(const float* __restrict__ xl,
                                                   const float* __restrict__ xr,
                                                   const float* __restrict__ att,
                                                   const float* __restrict__ bias,
                                                   const int* __restrict__ row_ptr,
                                                   const int* __restrict__ csr_src,
                                                   ushort* __restrict__ oh,
                                                   ushort* __restrict__ om,
                                                   ushort* __restrict__ ol,
                                                   float* __restrict__ of) {
    const int wave = threadIdx.x >> 6;
    const int lane = threadIdx.x & 63;
    const int node = blockIdx.x * 4 + wave;
    if (node >= NN) return;

    const float4 xri = ((const float4*)(xr + (size_t)node * 256))[lane];
    const float4 av  = ((const float4*)att)[lane];

    float m = -INFINITY, d = 0.f;
    float acc0 = 0.f, acc1 = 0.f, acc2 = 0.f, acc3 = 0.f;

    const int start = row_ptr[node];
    const int end   = row_ptr[node + 1];
    const int L = end - start + 1;   // + self-loop as last virtual edge

    int i = 0;
    for (; i + 1 < L; i += 2) {
        const int ea = start + i, eb = start + i + 1;
        const int sa = (ea < end) ? csr_src[ea] : node;
        const int sb = (eb < end) ? csr_src[eb] : node;
        const float4 xa = ((const float4*)(xl + (size_t)sa * 256))[lane];
        const float4 xb = ((const float4*)(xl + (size_t)sb * 256))[lane];
        float pa = av.x * lrelu(xa.x + xri.x) + av.y * lrelu(xa.y + xri.y)
                 + av.z * lrelu(xa.z + xri.z) + av.w * lrelu(xa.w + xri.w);
        float pb = av.x * lrelu(xb.x + xri.x) + av.y * lrelu(xb.y + xri.y)
                 + av.z * lrelu(xb.z + xri.z) + av.w * lrelu(xb.w + xri.w);
        pa += __shfl_xor(pa, 1); pb += __shfl_xor(pb, 1);
        pa += __shfl_xor(pa, 2); pb += __shfl_xor(pb, 2);
        pa += __shfl_xor(pa, 4); pb += __shfl_xor(pb, 4);
        pa += __shfl_xor(pa, 8); pb += __shfl_xor(pb, 8);

        const float mn    = fmaxf(m, fmaxf(pa, pb));
        const float scale = __expf(m - mn);
        const float fa    = __expf(pa - mn);
        const float fb    = __expf(pb - mn);
        d    = d * scale + fa + fb;
        acc0 = acc0 * scale + fa * xa.x + fb * xb.x;
        acc1 = acc1 * scale + fa * xa.y + fb * xb.y;
        acc2 = acc2 * scale + fa * xa.z + fb * xb.z;
        acc3 = acc3 * scale + fa * xa.w + fb * xb.w;
        m = mn;
    }
    if (i < L) {
        const int ea = start + i;
        const int sa = (ea < end) ? csr_src[ea] : node;
        const float4 xa = ((const float4*)(xl + (size_t)sa * 256))[lane];
        float pa = av.x * lrelu(xa.x + xri.x) + av.y * lrelu(xa.y + xri.y)
                 + av.z * lrelu(xa.z + xri.z) + av.w * lrelu(xa.w + xri.w);
        pa += __shfl_xor(pa, 1);
        pa += __shfl_xor(pa, 2);
        pa += __shfl_xor(pa, 4);
        pa += __shfl_xor(pa, 8);
        const float mn    = fmaxf(m, pa);
        const float scale = __expf(m - mn);
        const float fa    = __expf(pa - mn);
        d    = d * scale + fa;
        acc0 = acc0 * scale + fa * xa.x;
        acc1 = acc1 * scale + fa * xa.y;
        acc2 = acc2 * scale + fa * xa.z;
        acc3 = acc3 * scale + fa * xa.w;
        m = mn;
    }

    const float inv = 1.f / (d + 1e-16f);
    if (MODE == 0) {
        const int c = lane * 4;
        float v[4];
        v[0] = lrelu(acc0 * inv + bias[c + 0]);
        v[1] = lrelu(acc1 * inv + bias[c + 1]);
        v[2] = lrelu(acc2 * inv + bias[c + 2]);
        v[3] = lrelu(acc3 * inv + bias[c + 3]);
        ushort4 H, M4, L4;
        unsigned short* pH = &H.x; unsigned short* pM = &M4.x; unsigned short* pL = &L4.x;
#pragma unroll
        for (int j = 0; j < 4; ++j) {
            unsigned short h = f2bf(v[j]);
            float r1 = v[j] - bf2f(h);
            unsigned short mm = f2bf(r1);
            float r2 = r1 - bf2f(mm);
            pH[j] = h; pM[j] = mm; pL[j] = f2bf(r2);
        }
        const size_t o = (size_t)node * 64 + lane;   // ushort4 index
        ((ushort4*)oh)[o] = H;
        ((ushort4*)om)[o] = M4;
        ((ushort4*)ol)[o] = L4;
    } else {
        float v0 = acc0 * inv, v1 = acc1 * inv, v2 = acc2 * inv, v3 = acc3 * inv;
        v0 += __shfl_xor(v0, 16); v0 += __shfl_xor(v0, 32);
        v1 += __shfl_xor(v1, 16); v1 += __shfl_xor(v1, 32);
        v2 += __shfl_xor(v2, 16); v2 += __shfl_xor(v2, 32);
        v3 += __shfl_xor(v3, 16); v3 += __shfl_xor(v3, 32);
        if (lane < 16) {
            const int c = lane * 4;
            float4 o;
            o.x = v0 * 0.25f + bias[c + 0];
            o.y = v1 * 0.25f + bias[c + 1];
            o.z = v2 * 0.25f + bias[c + 2];
            o.w = v3 * 0.25f + bias[c + 3];
            ((float4*)(of + (size_t)node * 64))[lane] = o;
        }
    }
}

// ---------- global max pool (batch is sorted) ----------
#define PNB 32
__global__ __launch_bounds__(64) void k_pool(const float* __restrict__ h3,
                                             const int* __restrict__ batch,
                                             unsigned* gmax) {
    const int lane = threadIdx.x;
    const int start = blockIdx.x * PNB;
    if (start >= NN) return;
    const int end = min(start + PNB, NN);
    int curg = batch[start];
    float best = -INFINITY;
    for (int n = start; n < end; ++n) {
        int g = batch[n];
        if (g != curg) {
            atomicMax(&gmax[curg * 64 + lane], fenc(best));
            best = -INFINITY;
            curg = g;
        }
        best = fmaxf(best, h3[(size_t)n * 64 + lane]);
    }
    atomicMax(&gmax[curg * 64 + lane], fenc(best));
}

__global__ void k_decode(const unsigned* __restrict__ gmax, float* __restrict__ outg) {
    int i = blockIdx.x * blockDim.x + threadIdx.x;
    if (i < GG * 64) outg[i] = fdec(gmax[i]);
}

__global__ __launch_bounds__(128) void k_head(const float* __restrict__ g,
                                              const float* __restrict__ Wc,
                                              const float* __restrict__ bc,
                                              float* __restrict__ logits) {
    const int t = threadIdx.x;
    const int gr = t >> 1, o = t & 1;
    float s = bc[o];
    for (int c = 0; c < 64; ++c) s = fmaf(g[gr * 64 + c], Wc[c * 2 + o], s);
    logits[t] = s;
}

// ---------- launch ----------
extern "C" void kernel_launch(void* const* d_in, const int* in_sizes, int n_in,
                              void* d_out, int out_size, void* d_ws, size_t ws_size,
                              hipStream_t stream) {
    const float* x     = (const float*)d_in[0];
    const int*   ei    = (const int*)d_in[1];
    const int*   batch = (const int*)d_in[2];
    const float* Wl1 = (const float*)d_in[3];
    const float* Wr1 = (const float*)d_in[4];
    const float* att1 = (const float*)d_in[5];
    const float* b1  = (const float*)d_in[6];
    const float* Wl2 = (const float*)d_in[7];
    const float* Wr2 = (const float*)d_in[8];
    const float* att2 = (const float*)d_in[9];
    const float* b2  = (const float*)d_in[10];
    const float* Wl3 = (const float*)d_in[11];
    const float* Wr3 = (const float*)d_in[12];
    const float* att3 = (const float*)d_in[13];
    const float* b3  = (const float*)d_in[14];
    const float* Wc  = (const float*)d_in[15];
    const float* bc  = (const float*)d_in[16];
    float* out = (float*)d_out;   // [0..127]=logits, [128..4223]=g

    char* ws = (char*)d_ws;
    size_t off = 0;
    auto alloc = [&](size_t bytes) -> void* {
        void* p = ws + off;
        off += (bytes + 255) & ~(size_t)255;
        return p;
    };
    float*  xlout = (float*)alloc((size_t)NN * 256 * 4);
    float*  xrout = (float*)alloc((size_t)NN * 256 * 4);
    ushort* Ah    = (ushort*)alloc((size_t)NN * 256 * 2);
    ushort* Am    = (ushort*)alloc((size_t)NN * 256 * 2);
    ushort* Al    = (ushort*)alloc((size_t)NN * 256 * 2);
    // 6 weights x 3 planes, each padded to 256*256 bf16
    ushort* wt[6][3];
    for (int w = 0; w < 6; ++w)
        for (int s = 0; s < 3; ++s)
            wt[w][s] = (ushort*)alloc((size_t)256 * 256 * 2);
    int*   deg     = (int*)alloc((size_t)NN * 4);
    int*   cursor  = (int*)alloc((size_t)NN * 4);
    int*   row_ptr = (int*)alloc((size_t)(NN + 1) * 4);
    int*   csr_src = (int*)alloc((size_t)EE * 4);
    unsigned* gmax = (unsigned*)alloc((size_t)GG * 64 * 4);
    float* h3 = (float*)Ah;   // alias: Ah dead by the time agg<1> writes h3
    if (off > ws_size) return;

    const int* esrc = ei;
    const int* edst = ei + EE;

    // CSR build
    k_init<<<(NN + 255) / 256, 256, 0, stream>>>(deg, gmax);
    k_count<<<(EE + 255) / 256, 256, 0, stream>>>(edst, deg);
    k_scan<<<1, SCAN_T, 0, stream>>>(deg, row_ptr, cursor);
    k_scatter<<<(EE + 255) / 256, 256, 0, stream>>>(esrc, edst, cursor, csr_src);

    // splits
    k_xsplit<<<(NN * 128 / 4 + 255) / 256, 256, 0, stream>>>(x, Ah, Am, Al, NN * 128 / 4);
    const float* Ws[6] = {Wl1, Wr1, Wl2, Wr2, Wl3, Wr3};
    const int    Ks[6] = {128, 128, 256, 256, 256, 256};
    for (int w = 0; w < 6; ++w) {
        dim3 g(8, Ks[w] / 32), b(32, 8);
        k_wsplit<<<g, b, 0, stream>>>(Ws[w], Ks[w], wt[w][0], wt[w][1], wt[w][2]);
    }

    const dim3 gg((NN + GBM - 1) / GBM, 2);   // 313 x 2
    const int agg_blocks = NN / 4;

    // Layer 1 (K=128)
    gemm3<<<gg, 256, 0, stream>>>(Ah, Am, Al, wt[0][0], wt[0][1], wt[0][2], xlout, NN, 128);
    gemm3<<<gg, 256, 0, stream>>>(Ah, Am, Al, wt[1][0], wt[1][1], wt[1][2], xrout, NN, 128);
    k_aggregate<0><<<agg_blocks, 256, 0, stream>>>(xlout, xrout, att1, b1, row_ptr, csr_src,
                                                   Ah, Am, Al, nullptr);
    // Layer 2 (K=256)
    gemm3<<<gg, 256, 0, stream>>>(Ah, Am, Al, wt[2][0], wt[2][1], wt[2][2], xlout, NN, 256);
    gemm3<<<gg, 256, 0, stream>>>(Ah, Am, Al, wt[3][0], wt[3][1], wt[3][2], xrout, NN, 256);
    k_aggregate<0><<<agg_blocks, 256, 0, stream>>>(xlout, xrout, att2, b2, row_ptr, csr_src,
                                                   Ah, Am, Al, nullptr);
    // Layer 3 (K=256), mean over heads
    gemm3<<<gg, 256, 0, stream>>>(Ah, Am, Al, wt[4][0], wt[4][1], wt[4][2], xlout, NN, 256);
    gemm3<<<gg, 256, 0, stream>>>(Ah, Am, Al, wt[5][0], wt[5][1], wt[5][2], xrout, NN, 256);
    k_aggregate<1><<<agg_blocks, 256, 0, stream>>>(xlout, xrout, att3, b3, row_ptr, csr_src,
                                                   nullptr, nullptr, nullptr, h3);

    // Pool + head
    k_pool<<<(NN + PNB - 1) / PNB, 64, 0, stream>>>(h3, batch, gmax);
    k_decode<<<(GG * 64 + 255) / 256, 256, 0, stream>>>(gmax, out + 128);
    k_head<<<1, 128, 0, stream>>>(out + 128, Wc, bc, out);
}

// Round 7
// 721.237 us; speedup vs baseline: 1.4030x; 1.1174x over previous
//
#include <hip/hip_runtime.h>
#include <cstdint>

#define NN 40000
#define EE 640000
#define GG 64

typedef short bf16x8 __attribute__((ext_vector_type(8)));
typedef float f32x4 __attribute__((ext_vector_type(4)));

// ---------- helpers ----------
__device__ __forceinline__ float lrelu(float x) { return x > 0.f ? x : 0.2f * x; }

__device__ __forceinline__ unsigned short f2bf(float f) {
    unsigned u = __float_as_uint(f);
    return (unsigned short)((u + 0x7FFFu + ((u >> 16) & 1u)) >> 16);
}
__device__ __forceinline__ float bf2f(unsigned short h) {
    return __uint_as_float(((unsigned)h) << 16);
}

__device__ __forceinline__ unsigned fenc(float x) {
    unsigned u = __float_as_uint(x);
    return (u & 0x80000000u) ? ~u : (u | 0x80000000u);
}
__device__ __forceinline__ float fdec(unsigned e) {
    unsigned u = (e & 0x80000000u) ? (e ^ 0x80000000u) : ~e;
    return __uint_as_float(u);
}
#define ENC_NEG_INF 0x007FFFFFu

// async global->LDS, 16B per lane. LDS dest = wave-uniform base + lane*16.
// Generic->AS(3) conversion via addrspacecast (compiler emits the correct
// LDS-offset conversion) — NOT integer truncation of the flat address.
__device__ __forceinline__ void gload16(const void* g, void* l) {
    __builtin_amdgcn_global_load_lds(
        (const __attribute__((address_space(1))) unsigned int*)g,
        (__attribute__((address_space(3))) unsigned int*)l,
        16, 0, 0);
}

// ---------- CSR build ----------
__global__ void k_init(int* deg, unsigned* gmax) {
    int i = blockIdx.x * blockDim.x + threadIdx.x;
    if (i < NN) deg[i] = 0;
    if (i < GG * 64) gmax[i] = ENC_NEG_INF;
}

__global__ void k_count(const int* __restrict__ dst, int* deg) {
    int e = blockIdx.x * blockDim.x + threadIdx.x;
    if (e < EE) atomicAdd(&deg[dst[e]], 1);
}

#define SCAN_T 1024
__global__ __launch_bounds__(SCAN_T) void k_scan(const int* __restrict__ deg,
                                                 int* row_ptr, int* cursor) {
    __shared__ int part[SCAN_T];
    const int t = threadIdx.x;
    const int CH = (NN + SCAN_T - 1) / SCAN_T;
    const int base = t * CH;
    int s = 0;
    for (int j = 0; j < CH; ++j) {
        int idx = base + j;
        if (idx < NN) s += deg[idx];
    }
    part[t] = s;
    __syncthreads();
    for (int off = 1; off < SCAN_T; off <<= 1) {
        int v = (t >= off) ? part[t - off] : 0;
        __syncthreads();
        part[t] += v;
        __syncthreads();
    }
    int run = (t == 0) ? 0 : part[t - 1];
    for (int j = 0; j < CH; ++j) {
        int idx = base + j;
        if (idx < NN) {
            row_ptr[idx] = run;
            cursor[idx]  = run;
            run += deg[idx];
        }
    }
    if (t == SCAN_T - 1) row_ptr[NN] = run;
}

__global__ void k_scatter(const int* __restrict__ src, const int* __restrict__ dst,
                          int* cursor, int* csr_src) {
    int e = blockIdx.x * blockDim.x + threadIdx.x;
    if (e < EE) {
        int p = atomicAdd(&cursor[dst[e]], 1);
        csr_src[p] = src[e];
    }
}

// ---------- bf16x2 split of a dense f32 array ----------
__global__ void k_xsplit(const float* __restrict__ x,
                         ushort* __restrict__ ah, ushort* __restrict__ am, int total4) {
    int i = blockIdx.x * blockDim.x + threadIdx.x;
    if (i >= total4) return;
    float4 v = ((const float4*)x)[i];
    ushort4 H, M;
    float* pv = &v.x;
    unsigned short* pH = &H.x; unsigned short* pM = &M.x;
#pragma unroll
    for (int j = 0; j < 4; ++j) {
        float a = pv[j];
        unsigned short h = f2bf(a);
        pH[j] = h;
        pM[j] = f2bf(a - bf2f(h));
    }
    ((ushort4*)ah)[i] = H;
    ((ushort4*)am)[i] = M;
}

// ---------- transpose + bf16x2 split: W[K][256] f32 -> Wt{h,m}[256][K] bf16 ----------
__global__ __launch_bounds__(256) void k_wsplit(const float* __restrict__ W, int K,
                                                ushort* __restrict__ th,
                                                ushort* __restrict__ tm) {
    __shared__ float t[32][33];
    const int n0 = blockIdx.x * 32;
    const int k0 = blockIdx.y * 32;
    const int tx = threadIdx.x;
    const int ty = threadIdx.y;
#pragma unroll
    for (int i = 0; i < 4; ++i) {
        int kl = ty * 4 + i;
        t[kl][tx] = W[(size_t)(k0 + kl) * 256 + n0 + tx];
    }
    __syncthreads();
#pragma unroll
    for (int i = 0; i < 4; ++i) {
        int nl = ty * 4 + i;
        float a = t[tx][nl];
        unsigned short h = f2bf(a);
        size_t o = (size_t)(n0 + nl) * K + k0 + tx;
        th[o] = h;
        tm[o] = f2bf(a - bf2f(h));
    }
}

// ---------- bf16x2-split MFMA GEMM: C[M][256] = A[M][K] @ B[K][256] ----------
// A planes [M][K] bf16; B planes TRANSPOSED [256][K] bf16.
// 128x128 tile, BK=32, 4 waves of 64x64. Staging via global_load_lds w=16:
// LDS linear, global source pre-swizzled (chunk c = cs ^ ((row>>1)&3)).
// Products: h*h + h*m + m*h (m*m ~2^-18, dropped).
#define GBM 128
#define GBK 32
__global__ __launch_bounds__(256, 2) void gemm2(const ushort* __restrict__ Ah,
                                                const ushort* __restrict__ Am,
                                                const ushort* __restrict__ Bh,
                                                const ushort* __restrict__ Bm,
                                                float* __restrict__ C,
                                                int M, int K) {
    __shared__ ushort sAh[GBM * GBK];
    __shared__ ushort sAm[GBM * GBK];
    __shared__ ushort sBh[GBM * GBK];
    __shared__ ushort sBm[GBM * GBK];
    const int tid  = threadIdx.x;
    const int lane = tid & 63;
    const int wv   = tid >> 6;
    const int wm   = wv & 1;
    const int wn   = wv >> 1;
    const int bm   = blockIdx.x * GBM;
    const int bn   = blockIdx.y * 128;

    // wave -> staged tile (uniform selects, no memory-indexed arrays)
    const ushort* gsrc = (wv == 0) ? Ah : (wv == 1) ? Am : (wv == 2) ? Bh : Bm;
    ushort* lbase = (wv == 0) ? sAh : (wv == 1) ? sAm : (wv == 2) ? sBh : sBm;
    const int rowbase = (wv < 2) ? bm : bn;

    f32x4 acc[4][4];
#pragma unroll
    for (int i = 0; i < 4; ++i)
#pragma unroll
        for (int j = 0; j < 4; ++j)
            acc[i][j] = (f32x4){0.f, 0.f, 0.f, 0.f};

    const int rl = lane >> 2;       // staging row-in-group 0..15
    const int cs = lane & 3;        // staging LDS chunk slot 0..3
    const int fc = lane >> 4;       // fragment k-chunk 0..3
    const int fr = lane & 15;       // fragment row 0..15

    for (int k0 = 0; k0 < K; k0 += GBK) {
        // stage: each wave fills its 8KB tile with 8 gload_lds (1KB each)
#pragma unroll
        for (int j = 0; j < 8; ++j) {
            const int lrow = j * 16 + rl;
            const int c    = cs ^ ((lrow >> 1) & 3);   // pre-swizzled source chunk
            int grow = rowbase + lrow;
            grow = (grow >= M) ? (M - 1) : grow;       // only A tiles can trigger
            gload16(gsrc + (size_t)grow * K + k0 + c * 8, lbase + j * 512);
        }
        __syncthreads();   // drains vmcnt before barrier (compiler-inserted)

        bf16x8 aH[4], aM[4], bH[4], bM[4];
#pragma unroll
        for (int mi = 0; mi < 4; ++mi) {
            const int row = wm * 64 + mi * 16 + fr;
            const int idx = row * 32 + (fc ^ ((row >> 1) & 3)) * 8;
            aH[mi] = *(const bf16x8*)&sAh[idx];
            aM[mi] = *(const bf16x8*)&sAm[idx];
        }
#pragma unroll
        for (int ni = 0; ni < 4; ++ni) {
            const int row = wn * 64 + ni * 16 + fr;
            const int idx = row * 32 + (fc ^ ((row >> 1) & 3)) * 8;
            bH[ni] = *(const bf16x8*)&sBh[idx];
            bM[ni] = *(const bf16x8*)&sBm[idx];
        }

#pragma unroll
        for (int mi = 0; mi < 4; ++mi)
#pragma unroll
            for (int ni = 0; ni < 4; ++ni) {
                f32x4 c0 = acc[mi][ni];
                c0 = __builtin_amdgcn_mfma_f32_16x16x32_bf16(aH[mi], bH[ni], c0, 0, 0, 0);
                c0 = __builtin_amdgcn_mfma_f32_16x16x32_bf16(aH[mi], bM[ni], c0, 0, 0, 0);
                c0 = __builtin_amdgcn_mfma_f32_16x16x32_bf16(aM[mi], bH[ni], c0, 0, 0, 0);
                acc[mi][ni] = c0;
            }
        __syncthreads();
    }

    // epilogue: C/D layout col=lane&15, row=(lane>>4)*4+reg (verified r4)
#pragma unroll
    for (int mi = 0; mi < 4; ++mi) {
#pragma unroll
        for (int r = 0; r < 4; ++r) {
            const int row = bm + wm * 64 + mi * 16 + (lane >> 4) * 4 + r;
            if (row < M) {
#pragma unroll
                for (int ni = 0; ni < 4; ++ni) {
                    const int col = bn + wn * 64 + ni * 16 + (lane & 15);
                    C[(size_t)row * 256 + col] = acc[mi][ni][r];
                }
            }
        }
    }
}

// ---------- fused GATv2 edge-softmax aggregation ----------
// One wave per node; lane l owns flat channels 4l..4l+3 (head = l>>4).
// 4-edge unroll (4 gathers in flight) + defer-max (THR=8): the rescale
// branch is wave-uniform and rarely taken.
// MODE 0: concat 4 heads + bias + LeakyReLU, bf16x2-split output
// MODE 1: mean over 4 heads (64 out) + bias, f32 output
template <int MODE>
__global__ __launch_bounds__(256) void k_aggregate(const float* __restrict__ xl,
                                                   const float* __restrict__ xr,
                                                   const float* __restrict__ att,
                                                   const float* __restrict__ bias,
                                                   const int* __restrict__ row_ptr,
                                                   const int* __restrict__ csr_src,
                                                   ushort* __restrict__ oh,
                                                   ushort* __restrict__ om,
                                                   float* __restrict__ of) {
    const int wave = threadIdx.x >> 6;
    const int lane = threadIdx.x & 63;
    const int node = blockIdx.x * 4 + wave;
    if (node >= NN) return;

    const float4 xri = ((const float4*)(xr + (size_t)node * 256))[lane];
    const float4 av  = ((const float4*)att)[lane];

    float m = -INFINITY, d = 0.f;
    float a0 = 0.f, a1 = 0.f, a2 = 0.f, a3 = 0.f;

    const int start = row_ptr[node];
    const int endp  = row_ptr[node + 1];
    const int L = endp - start + 1;   // + self-loop as last virtual edge

    int i = 0;
    for (; i + 4 <= L; i += 4) {
        const int e0 = start + i;
        const int s0 = (e0     < endp) ? csr_src[e0]     : node;
        const int s1 = (e0 + 1 < endp) ? csr_src[e0 + 1] : node;
        const int s2 = (e0 + 2 < endp) ? csr_src[e0 + 2] : node;
        const int s3 = (e0 + 3 < endp) ? csr_src[e0 + 3] : node;
        const float4 x0 = ((const float4*)(xl + (size_t)s0 * 256))[lane];
        const float4 x1 = ((const float4*)(xl + (size_t)s1 * 256))[lane];
        const float4 x2 = ((const float4*)(xl + (size_t)s2 * 256))[lane];
        const float4 x3 = ((const float4*)(xl + (size_t)s3 * 256))[lane];
        float p0 = av.x * lrelu(x0.x + xri.x) + av.y * lrelu(x0.y + xri.y)
                 + av.z * lrelu(x0.z + xri.z) + av.w * lrelu(x0.w + xri.w);
        float p1 = av.x * lrelu(x1.x + xri.x) + av.y * lrelu(x1.y + xri.y)
                 + av.z * lrelu(x1.z + xri.z) + av.w * lrelu(x1.w + xri.w);
        float p2 = av.x * lrelu(x2.x + xri.x) + av.y * lrelu(x2.y + xri.y)
                 + av.z * lrelu(x2.z + xri.z) + av.w * lrelu(x2.w + xri.w);
        float p3 = av.x * lrelu(x3.x + xri.x) + av.y * lrelu(x3.y + xri.y)
                 + av.z * lrelu(x3.z + xri.z) + av.w * lrelu(x3.w + xri.w);
        p0 += __shfl_xor(p0, 1); p1 += __shfl_xor(p1, 1);
        p2 += __shfl_xor(p2, 1); p3 += __shfl_xor(p3, 1);
        p0 += __shfl_xor(p0, 2); p1 += __shfl_xor(p1, 2);
        p2 += __shfl_xor(p2, 2); p3 += __shfl_xor(p3, 2);
        p0 += __shfl_xor(p0, 4); p1 += __shfl_xor(p1, 4);
        p2 += __shfl_xor(p2, 4); p3 += __shfl_xor(p3, 4);
        p0 += __shfl_xor(p0, 8); p1 += __shfl_xor(p1, 8);
        p2 += __shfl_xor(p2, 8); p3 += __shfl_xor(p3, 8);

        const float pm = fmaxf(fmaxf(p0, p1), fmaxf(p2, p3));
        if (__all(pm <= m + 8.f)) {      // defer-max fast path (P bounded by e^8)
            const float f0 = __expf(p0 - m), f1 = __expf(p1 - m);
            const float f2 = __expf(p2 - m), f3 = __expf(p3 - m);
            d  += f0 + f1 + f2 + f3;
            a0 += f0 * x0.x + f1 * x1.x + f2 * x2.x + f3 * x3.x;
            a1 += f0 * x0.y + f1 * x1.y + f2 * x2.y + f3 * x3.y;
            a2 += f0 * x0.z + f1 * x1.z + f2 * x2.z + f3 * x3.z;
            a3 += f0 * x0.w + f1 * x1.w + f2 * x2.w + f3 * x3.w;
        } else {
            const float mn = fmaxf(m, pm);
            const float sc = __expf(m - mn);   // m=-inf first iter -> 0
            const float f0 = __expf(p0 - mn), f1 = __expf(p1 - mn);
            const float f2 = __expf(p2 - mn), f3 = __expf(p3 - mn);
            d  = d  * sc + f0 + f1 + f2 + f3;
            a0 = a0 * sc + f0 * x0.x + f1 * x1.x + f2 * x2.x + f3 * x3.x;
            a1 = a1 * sc + f0 * x0.y + f1 * x1.y + f2 * x2.y + f3 * x3.y;
            a2 = a2 * sc + f0 * x0.z + f1 * x1.z + f2 * x2.z + f3 * x3.z;
            a3 = a3 * sc + f0 * x0.w + f1 * x1.w + f2 * x2.w + f3 * x3.w;
            m = mn;
        }
    }
    for (; i < L; ++i) {   // tail (1..3 edges incl. self-loop)
        const int e0 = start + i;
        const int s0 = (e0 < endp) ? csr_src[e0] : node;
        const float4 x0 = ((const float4*)(xl + (size_t)s0 * 256))[lane];
        float p0 = av.x * lrelu(x0.x + xri.x) + av.y * lrelu(x0.y + xri.y)
                 + av.z * lrelu(x0.z + xri.z) + av.w * lrelu(x0.w + xri.w);
        p0 += __shfl_xor(p0, 1);
        p0 += __shfl_xor(p0, 2);
        p0 += __shfl_xor(p0, 4);
        p0 += __shfl_xor(p0, 8);
        if (__all(p0 <= m + 8.f)) {
            const float f0 = __expf(p0 - m);
            d += f0; a0 += f0 * x0.x; a1 += f0 * x0.y; a2 += f0 * x0.z; a3 += f0 * x0.w;
        } else {
            const float mn = fmaxf(m, p0);
            const float sc = __expf(m - mn);
            const float f0 = __expf(p0 - mn);
            d  = d  * sc + f0;
            a0 = a0 * sc + f0 * x0.x;
            a1 = a1 * sc + f0 * x0.y;
            a2 = a2 * sc + f0 * x0.z;
            a3 = a3 * sc + f0 * x0.w;
            m = mn;
        }
    }

    const float inv = 1.f / (d + 1e-16f);
    if (MODE == 0) {
        const int c = lane * 4;
        float v[4];
        v[0] = lrelu(a0 * inv + bias[c + 0]);
        v[1] = lrelu(a1 * inv + bias[c + 1]);
        v[2] = lrelu(a2 * inv + bias[c + 2]);
        v[3] = lrelu(a3 * inv + bias[c + 3]);
        ushort4 H, M4;
        unsigned short* pH = &H.x; unsigned short* pM = &M4.x;
#pragma unroll
        for (int j = 0; j < 4; ++j) {
            unsigned short h = f2bf(v[j]);
            pH[j] = h;
            pM[j] = f2bf(v[j] - bf2f(h));
        }
        const size_t o = (size_t)node * 64 + lane;   // ushort4 index
        ((ushort4*)oh)[o] = H;
        ((ushort4*)om)[o] = M4;
    } else {
        float v0 = a0 * inv, v1 = a1 * inv, v2 = a2 * inv, v3 = a3 * inv;
        v0 += __shfl_xor(v0, 16); v0 += __shfl_xor(v0, 32);
        v1 += __shfl_xor(v1, 16); v1 += __shfl_xor(v1, 32);
        v2 += __shfl_xor(v2, 16); v2 += __shfl_xor(v2, 32);
        v3 += __shfl_xor(v3, 16); v3 += __shfl_xor(v3, 32);
        if (lane < 16) {
            const int c = lane * 4;
            float4 o;
            o.x = v0 * 0.25f + bias[c + 0];
            o.y = v1 * 0.25f + bias[c + 1];
            o.z = v2 * 0.25f + bias[c + 2];
            o.w = v3 * 0.25f + bias[c + 3];
            ((float4*)(of + (size_t)node * 64))[lane] = o;
        }
    }
}

// ---------- global max pool (batch is sorted) ----------
#define PNB 32
__global__ __launch_bounds__(64) void k_pool(const float* __restrict__ h3,
                                             const int* __restrict__ batch,
                                             unsigned* gmax) {
    const int lane = threadIdx.x;
    const int start = blockIdx.x * PNB;
    if (start >= NN) return;
    const int end = min(start + PNB, NN);
    int curg = batch[start];
    float best = -INFINITY;
    for (int n = start; n < end; ++n) {
        int g = batch[n];
        if (g != curg) {
            atomicMax(&gmax[curg * 64 + lane], fenc(best));
            best = -INFINITY;
            curg = g;
        }
        best = fmaxf(best, h3[(size_t)n * 64 + lane]);
    }
    atomicMax(&gmax[curg * 64 + lane], fenc(best));
}

__global__ void k_decode(const unsigned* __restrict__ gmax, float* __restrict__ outg) {
    int i = blockIdx.x * blockDim.x + threadIdx.x;
    if (i < GG * 64) outg[i] = fdec(gmax[i]);
}

__global__ __launch_bounds__(128) void k_head(const float* __restrict__ g,
                                              const float* __restrict__ Wc,
                                              const float* __restrict__ bc,
                                              float* __restrict__ logits) {
    const int t = threadIdx.x;
    const int gr = t >> 1, o = t & 1;
    float s = bc[o];
    for (int c = 0; c < 64; ++c) s = fmaf(g[gr * 64 + c], Wc[c * 2 + o], s);
    logits[t] = s;
}

// ---------- launch ----------
extern "C" void kernel_launch(void* const* d_in, const int* in_sizes, int n_in,
                              void* d_out, int out_size, void* d_ws, size_t ws_size,
                              hipStream_t stream) {
    const float* x     = (const float*)d_in[0];
    const int*   ei    = (const int*)d_in[1];
    const int*   batch = (const int*)d_in[2];
    const float* Wl1 = (const float*)d_in[3];
    const float* Wr1 = (const float*)d_in[4];
    const float* att1 = (const float*)d_in[5];
    const float* b1  = (const float*)d_in[6];
    const float* Wl2 = (const float*)d_in[7];
    const float* Wr2 = (const float*)d_in[8];
    const float* att2 = (const float*)d_in[9];
    const float* b2  = (const float*)d_in[10];
    const float* Wl3 = (const float*)d_in[11];
    const float* Wr3 = (const float*)d_in[12];
    const float* att3 = (const float*)d_in[13];
    const float* b3  = (const float*)d_in[14];
    const float* Wc  = (const float*)d_in[15];
    const float* bc  = (const float*)d_in[16];
    float* out = (float*)d_out;   // [0..127]=logits, [128..4223]=g

    char* ws = (char*)d_ws;
    size_t off = 0;
    auto alloc = [&](size_t bytes) -> void* {
        void* p = ws + off;
        off += (bytes + 255) & ~(size_t)255;
        return p;
    };
    float*  xlout = (float*)alloc((size_t)NN * 256 * 4);
    float*  xrout = (float*)alloc((size_t)NN * 256 * 4);
    ushort* Ah    = (ushort*)alloc((size_t)NN * 256 * 2);
    ushort* Am    = (ushort*)alloc((size_t)NN * 256 * 2);
    ushort* wt[6][2];
    for (int w = 0; w < 6; ++w)
        for (int s = 0; s < 2; ++s)
            wt[w][s] = (ushort*)alloc((size_t)256 * 256 * 2);
    int*   deg     = (int*)alloc((size_t)NN * 4);
    int*   cursor  = (int*)alloc((size_t)NN * 4);
    int*   row_ptr = (int*)alloc((size_t)(NN + 1) * 4);
    int*   csr_src = (int*)alloc((size_t)EE * 4);
    unsigned* gmax = (unsigned*)alloc((size_t)GG * 64 * 4);
    float* h3 = (float*)Ah;   // alias: Ah dead once layer-3 GEMMs have read it
    if (off > ws_size) return;

    const int* esrc = ei;
    const int* edst = ei + EE;

    // CSR build (graph identical across layers)
    k_init<<<(NN + 255) / 256, 256, 0, stream>>>(deg, gmax);
    k_count<<<(EE + 255) / 256, 256, 0, stream>>>(edst, deg);
    k_scan<<<1, SCAN_T, 0, stream>>>(deg, row_ptr, cursor);
    k_scatter<<<(EE + 255) / 256, 256, 0, stream>>>(esrc, edst, cursor, csr_src);

    // splits
    k_xsplit<<<(NN * 128 / 4 + 255) / 256, 256, 0, stream>>>(x, Ah, Am, NN * 128 / 4);
    const float* Ws[6] = {Wl1, Wr1, Wl2, Wr2, Wl3, Wr3};
    const int    Ks[6] = {128, 128, 256, 256, 256, 256};
    for (int w = 0; w < 6; ++w) {
        dim3 g(8, Ks[w] / 32), b(32, 8);
        k_wsplit<<<g, b, 0, stream>>>(Ws[w], Ks[w], wt[w][0], wt[w][1]);
    }

    const dim3 gg((NN + GBM - 1) / GBM, 2);   // 313 x 2
    const int agg_blocks = NN / 4;

    // Layer 1 (K=128)
    gemm2<<<gg, 256, 0, stream>>>(Ah, Am, wt[0][0], wt[0][1], xlout, NN, 128);
    gemm2<<<gg, 256, 0, stream>>>(Ah, Am, wt[1][0], wt[1][1], xrout, NN, 128);
    k_aggregate<0><<<agg_blocks, 256, 0, stream>>>(xlout, xrout, att1, b1, row_ptr, csr_src,
                                                   Ah, Am, nullptr);
    // Layer 2 (K=256)
    gemm2<<<gg, 256, 0, stream>>>(Ah, Am, wt[2][0], wt[2][1], xlout, NN, 256);
    gemm2<<<gg, 256, 0, stream>>>(Ah, Am, wt[3][0], wt[3][1], xrout, NN, 256);
    k_aggregate<0><<<agg_blocks, 256, 0, stream>>>(xlout, xrout, att2, b2, row_ptr, csr_src,
                                                   Ah, Am, nullptr);
    // Layer 3 (K=256), mean over heads
    gemm2<<<gg, 256, 0, stream>>>(Ah, Am, wt[4][0], wt[4][1], xlout, NN, 256);
    gemm2<<<gg, 256, 0, stream>>>(Ah, Am, wt[5][0], wt[5][1], xrout, NN, 256);
    k_aggregate<1><<<agg_blocks, 256, 0, stream>>>(xlout, xrout, att3, b3, row_ptr, csr_src,
                                                   nullptr, nullptr, h3);

    // Pool + head
    k_pool<<<(NN + PNB - 1) / PNB, 64, 0, stream>>>(h3, batch, gmax);
    k_decode<<<(GG * 64 + 255) / 256, 256, 0, stream>>>(gmax, out + 128);
    k_head<<<1, 128, 0, stream>>>(out + 128, Wc, bc, out);
}

// Round 8
// 705.743 us; speedup vs baseline: 1.4338x; 1.0220x over previous
//
#include <hip/hip_runtime.h>
#include <cstdint>

#define NN 40000
#define EE 640000
#define GG 64

typedef short bf16x8 __attribute__((ext_vector_type(8)));
typedef float f32x4 __attribute__((ext_vector_type(4)));

// ---------- helpers ----------
__device__ __forceinline__ float lrelu(float x) { return x > 0.f ? x : 0.2f * x; }

__device__ __forceinline__ unsigned short f2bf(float f) {
    unsigned u = __float_as_uint(f);
    return (unsigned short)((u + 0x7FFFu + ((u >> 16) & 1u)) >> 16);
}
__device__ __forceinline__ float bf2f(unsigned short h) {
    return __uint_as_float(((unsigned)h) << 16);
}

__device__ __forceinline__ unsigned fenc(float x) {
    unsigned u = __float_as_uint(x);
    return (u & 0x80000000u) ? ~u : (u | 0x80000000u);
}
__device__ __forceinline__ float fdec(unsigned e) {
    unsigned u = (e & 0x80000000u) ? (e ^ 0x80000000u) : ~e;
    return __uint_as_float(u);
}
#define ENC_NEG_INF 0x007FFFFFu

// async global->LDS, 16B per lane (addrspacecast form — verified r7)
__device__ __forceinline__ void gload16(const void* g, void* l) {
    __builtin_amdgcn_global_load_lds(
        (const __attribute__((address_space(1))) unsigned int*)g,
        (__attribute__((address_space(3))) unsigned int*)l,
        16, 0, 0);
}

// ---------- CSR build ----------
__global__ void k_init(int* deg, unsigned* gmax) {
    int i = blockIdx.x * blockDim.x + threadIdx.x;
    if (i < NN) deg[i] = 0;
    if (i < GG * 64) gmax[i] = ENC_NEG_INF;
}

__global__ void k_count(const int* __restrict__ dst, int* deg) {
    int e = blockIdx.x * blockDim.x + threadIdx.x;
    if (e < EE) atomicAdd(&deg[dst[e]], 1);
}

#define SCAN_T 1024
__global__ __launch_bounds__(SCAN_T) void k_scan(const int* __restrict__ deg,
                                                 int* row_ptr, int* cursor) {
    __shared__ int part[SCAN_T];
    const int t = threadIdx.x;
    const int CH = (NN + SCAN_T - 1) / SCAN_T;
    const int base = t * CH;
    int s = 0;
    for (int j = 0; j < CH; ++j) {
        int idx = base + j;
        if (idx < NN) s += deg[idx];
    }
    part[t] = s;
    __syncthreads();
    for (int off = 1; off < SCAN_T; off <<= 1) {
        int v = (t >= off) ? part[t - off] : 0;
        __syncthreads();
        part[t] += v;
        __syncthreads();
    }
    int run = (t == 0) ? 0 : part[t - 1];
    for (int j = 0; j < CH; ++j) {
        int idx = base + j;
        if (idx < NN) {
            row_ptr[idx] = run;
            cursor[idx]  = run;
            run += deg[idx];
        }
    }
    if (t == SCAN_T - 1) row_ptr[NN] = run;
}

__global__ void k_scatter(const int* __restrict__ src, const int* __restrict__ dst,
                          int* cursor, int* csr_src) {
    int e = blockIdx.x * blockDim.x + threadIdx.x;
    if (e < EE) {
        int p = atomicAdd(&cursor[dst[e]], 1);
        csr_src[p] = src[e];
    }
}

// ---------- bf16x2 split of a dense f32 array ----------
__global__ void k_xsplit(const float* __restrict__ x,
                         ushort* __restrict__ ah, ushort* __restrict__ am, int total4) {
    int i = blockIdx.x * blockDim.x + threadIdx.x;
    if (i >= total4) return;
    float4 v = ((const float4*)x)[i];
    ushort4 H, M;
    float* pv = &v.x;
    unsigned short* pH = &H.x; unsigned short* pM = &M.x;
#pragma unroll
    for (int j = 0; j < 4; ++j) {
        float a = pv[j];
        unsigned short h = f2bf(a);
        pH[j] = h;
        pM[j] = f2bf(a - bf2f(h));
    }
    ((ushort4*)ah)[i] = H;
    ((ushort4*)am)[i] = M;
}

// ---------- transpose + bf16x2 split: W[K][256] f32 -> combined Wt{h,m}[512][K] bf16 ----------
// woff selects rows [woff, woff+256) of the combined transposed buffer.
__global__ __launch_bounds__(256) void k_wsplit(const float* __restrict__ W, int K, int woff,
                                                ushort* __restrict__ th,
                                                ushort* __restrict__ tm) {
    __shared__ float t[32][33];
    const int n0 = blockIdx.x * 32;
    const int k0 = blockIdx.y * 32;
    const int tx = threadIdx.x;
    const int ty = threadIdx.y;
#pragma unroll
    for (int i = 0; i < 4; ++i) {
        int kl = ty * 4 + i;
        t[kl][tx] = W[(size_t)(k0 + kl) * 256 + n0 + tx];
    }
    __syncthreads();
#pragma unroll
    for (int i = 0; i < 4; ++i) {
        int nl = ty * 4 + i;
        float a = t[tx][nl];
        unsigned short h = f2bf(a);
        size_t o = (size_t)(woff + n0 + nl) * K + k0 + tx;
        th[o] = h;
        tm[o] = f2bf(a - bf2f(h));
    }
}

// ---------- bf16x2-split MFMA GEMM (combined): C[M][512] = A[M][K] @ B[K][512] ----------
// A planes [M][K]; B planes TRANSPOSED [512][K]. 128x128 tile, BK=32, 4 waves
// of 64x64. Double-buffered LDS + 2-phase prefetch: STAGE(next) issued before
// compute(cur); trailing __syncthreads (vmcnt(0)+barrier) lands after compute.
// Products: h*h + h*m + m*h.
#define GBM 128
#define GBK 32
__global__ __launch_bounds__(256, 2) void gemm2c(const ushort* __restrict__ Ah,
                                                 const ushort* __restrict__ Am,
                                                 const ushort* __restrict__ Bh,
                                                 const ushort* __restrict__ Bm,
                                                 float* __restrict__ C,
                                                 int M, int K) {
    __shared__ ushort sAh[2][GBM * GBK];
    __shared__ ushort sAm[2][GBM * GBK];
    __shared__ ushort sBh[2][GBM * GBK];
    __shared__ ushort sBm[2][GBM * GBK];
    const int tid  = threadIdx.x;
    const int lane = tid & 63;
    const int wv   = tid >> 6;
    const int wm   = wv & 1;
    const int wn   = wv >> 1;
    const int bm   = blockIdx.x * GBM;
    const int bn   = blockIdx.y * 128;          // 0..384

    // wave -> staged tile (uniform selects)
    const ushort* gsrc = (wv == 0) ? Ah : (wv == 1) ? Am : (wv == 2) ? Bh : Bm;
    ushort* l0 = (wv == 0) ? sAh[0] : (wv == 1) ? sAm[0] : (wv == 2) ? sBh[0] : sBm[0];
    ushort* l1 = (wv == 0) ? sAh[1] : (wv == 1) ? sAm[1] : (wv == 2) ? sBh[1] : sBm[1];
    const int rowbase = (wv < 2) ? bm : bn;

    f32x4 acc[4][4];
#pragma unroll
    for (int i = 0; i < 4; ++i)
#pragma unroll
        for (int j = 0; j < 4; ++j)
            acc[i][j] = (f32x4){0.f, 0.f, 0.f, 0.f};

    const int rl = lane >> 2;       // staging row-in-group 0..15
    const int cs = lane & 3;        // staging LDS chunk slot 0..3
    const int fc = lane >> 4;       // fragment k-chunk 0..3
    const int fr = lane & 15;       // fragment row 0..15

    auto stage = [&](ushort* lb, int kt) {
        const int k0 = kt * GBK;
#pragma unroll
        for (int j = 0; j < 8; ++j) {
            const int lrow = j * 16 + rl;
            const int c    = cs ^ ((lrow >> 1) & 3);   // pre-swizzled source chunk
            int grow = rowbase + lrow;
            grow = (grow >= M) ? (M - 1) : grow;       // only A tiles can trigger
            gload16(gsrc + (size_t)grow * K + k0 + c * 8, lb + j * 512);
        }
    };

    stage(l0, 0);
    __syncthreads();                 // vmcnt(0) drain + barrier (prologue tile ready)

    const int nt = K / GBK;
    for (int t = 0; t < nt; ++t) {
        if (t + 1 < nt) stage((t & 1) ? l0 : l1, t + 1);   // issue next-tile loads

        const int b = t & 1;
        const ushort* pAh = sAh[b];
        const ushort* pAm = sAm[b];
        const ushort* pBh = sBh[b];
        const ushort* pBm = sBm[b];

        bf16x8 aH[4], aM[4], bH[4], bM[4];
#pragma unroll
        for (int mi = 0; mi < 4; ++mi) {
            const int row = wm * 64 + mi * 16 + fr;
            const int idx = row * 32 + (fc ^ ((row >> 1) & 3)) * 8;
            aH[mi] = *(const bf16x8*)&pAh[idx];
            aM[mi] = *(const bf16x8*)&pAm[idx];
        }
#pragma unroll
        for (int ni = 0; ni < 4; ++ni) {
            const int row = wn * 64 + ni * 16 + fr;
            const int idx = row * 32 + (fc ^ ((row >> 1) & 3)) * 8;
            bH[ni] = *(const bf16x8*)&pBh[idx];
            bM[ni] = *(const bf16x8*)&pBm[idx];
        }

#pragma unroll
        for (int mi = 0; mi < 4; ++mi)
#pragma unroll
            for (int ni = 0; ni < 4; ++ni) {
                f32x4 c0 = acc[mi][ni];
                c0 = __builtin_amdgcn_mfma_f32_16x16x32_bf16(aH[mi], bH[ni], c0, 0, 0, 0);
                c0 = __builtin_amdgcn_mfma_f32_16x16x32_bf16(aH[mi], bM[ni], c0, 0, 0, 0);
                c0 = __builtin_amdgcn_mfma_f32_16x16x32_bf16(aM[mi], bH[ni], c0, 0, 0, 0);
                acc[mi][ni] = c0;
            }
        __syncthreads();   // drains next-tile loads (hidden under compute) + barrier
    }

    // epilogue: C/D layout col=lane&15, row=(lane>>4)*4+reg ; C stride 512
#pragma unroll
    for (int mi = 0; mi < 4; ++mi) {
#pragma unroll
        for (int r = 0; r < 4; ++r) {
            const int row = bm + wm * 64 + mi * 16 + (lane >> 4) * 4 + r;
            if (row < M) {
#pragma unroll
                for (int ni = 0; ni < 4; ++ni) {
                    const int col = bn + wn * 64 + ni * 16 + (lane & 15);
                    C[(size_t)row * 512 + col] = acc[mi][ni][r];
                }
            }
        }
    }
}

// ---------- fused GATv2 edge-softmax aggregation ----------
// xlr[M][512]: cols 0..255 = xl (source transform), 256..511 = xr (target).
// One wave per node; lane l owns flat channels 4l..4l+3 (head = l>>4).
// 4-edge unroll + defer-max (THR=8).
// MODE 0: concat 4 heads + bias + LeakyReLU, bf16x2-split output
// MODE 1: mean over 4 heads (64 out) + bias, f32 output
template <int MODE>
__global__ __launch_bounds__(256) void k_aggregate(const float* __restrict__ xlr,
                                                   const float* __restrict__ att,
                                                   const float* __restrict__ bias,
                                                   const int* __restrict__ row_ptr,
                                                   const int* __restrict__ csr_src,
                                                   ushort* __restrict__ oh,
                                                   ushort* __restrict__ om,
                                                   float* __restrict__ of) {
    const int wave = threadIdx.x >> 6;
    const int lane = threadIdx.x & 63;
    const int node = blockIdx.x * 4 + wave;
    if (node >= NN) return;

    const float4 xri = ((const float4*)(xlr + (size_t)node * 512 + 256))[lane];
    const float4 av  = ((const float4*)att)[lane];

    float m = -INFINITY, d = 0.f;
    float a0 = 0.f, a1 = 0.f, a2 = 0.f, a3 = 0.f;

    const int start = row_ptr[node];
    const int endp  = row_ptr[node + 1];
    const int L = endp - start + 1;   // + self-loop as last virtual edge

    int i = 0;
    for (; i + 4 <= L; i += 4) {
        const int e0 = start + i;
        const int s0 = (e0     < endp) ? csr_src[e0]     : node;
        const int s1 = (e0 + 1 < endp) ? csr_src[e0 + 1] : node;
        const int s2 = (e0 + 2 < endp) ? csr_src[e0 + 2] : node;
        const int s3 = (e0 + 3 < endp) ? csr_src[e0 + 3] : node;
        const float4 x0 = ((const float4*)(xlr + (size_t)s0 * 512))[lane];
        const float4 x1 = ((const float4*)(xlr + (size_t)s1 * 512))[lane];
        const float4 x2 = ((const float4*)(xlr + (size_t)s2 * 512))[lane];
        const float4 x3 = ((const float4*)(xlr + (size_t)s3 * 512))[lane];
        float p0 = av.x * lrelu(x0.x + xri.x) + av.y * lrelu(x0.y + xri.y)
                 + av.z * lrelu(x0.z + xri.z) + av.w * lrelu(x0.w + xri.w);
        float p1 = av.x * lrelu(x1.x + xri.x) + av.y * lrelu(x1.y + xri.y)
                 + av.z * lrelu(x1.z + xri.z) + av.w * lrelu(x1.w + xri.w);
        float p2 = av.x * lrelu(x2.x + xri.x) + av.y * lrelu(x2.y + xri.y)
                 + av.z * lrelu(x2.z + xri.z) + av.w * lrelu(x2.w + xri.w);
        float p3 = av.x * lrelu(x3.x + xri.x) + av.y * lrelu(x3.y + xri.y)
                 + av.z * lrelu(x3.z + xri.z) + av.w * lrelu(x3.w + xri.w);
        p0 += __shfl_xor(p0, 1); p1 += __shfl_xor(p1, 1);
        p2 += __shfl_xor(p2, 1); p3 += __shfl_xor(p3, 1);
        p0 += __shfl_xor(p0, 2); p1 += __shfl_xor(p1, 2);
        p2 += __shfl_xor(p2, 2); p3 += __shfl_xor(p3, 2);
        p0 += __shfl_xor(p0, 4); p1 += __shfl_xor(p1, 4);
        p2 += __shfl_xor(p2, 4); p3 += __shfl_xor(p3, 4);
        p0 += __shfl_xor(p0, 8); p1 += __shfl_xor(p1, 8);
        p2 += __shfl_xor(p2, 8); p3 += __shfl_xor(p3, 8);

        const float pm = fmaxf(fmaxf(p0, p1), fmaxf(p2, p3));
        if (__all(pm <= m + 8.f)) {      // defer-max fast path
            const float f0 = __expf(p0 - m), f1 = __expf(p1 - m);
            const float f2 = __expf(p2 - m), f3 = __expf(p3 - m);
            d  += f0 + f1 + f2 + f3;
            a0 += f0 * x0.x + f1 * x1.x + f2 * x2.x + f3 * x3.x;
            a1 += f0 * x0.y + f1 * x1.y + f2 * x2.y + f3 * x3.y;
            a2 += f0 * x0.z + f1 * x1.z + f2 * x2.z + f3 * x3.z;
            a3 += f0 * x0.w + f1 * x1.w + f2 * x2.w + f3 * x3.w;
        } else {
            const float mn = fmaxf(m, pm);
            const float sc = __expf(m - mn);   // m=-inf first iter -> 0
            const float f0 = __expf(p0 - mn), f1 = __expf(p1 - mn);
            const float f2 = __expf(p2 - mn), f3 = __expf(p3 - mn);
            d  = d  * sc + f0 + f1 + f2 + f3;
            a0 = a0 * sc + f0 * x0.x + f1 * x1.x + f2 * x2.x + f3 * x3.x;
            a1 = a1 * sc + f0 * x0.y + f1 * x1.y + f2 * x2.y + f3 * x3.y;
            a2 = a2 * sc + f0 * x0.z + f1 * x1.z + f2 * x2.z + f3 * x3.z;
            a3 = a3 * sc + f0 * x0.w + f1 * x1.w + f2 * x2.w + f3 * x3.w;
            m = mn;
        }
    }
    for (; i < L; ++i) {   // tail (1..3 edges incl. self-loop)
        const int e0 = start + i;
        const int s0 = (e0 < endp) ? csr_src[e0] : node;
        const float4 x0 = ((const float4*)(xlr + (size_t)s0 * 512))[lane];
        float p0 = av.x * lrelu(x0.x + xri.x) + av.y * lrelu(x0.y + xri.y)
                 + av.z * lrelu(x0.z + xri.z) + av.w * lrelu(x0.w + xri.w);
        p0 += __shfl_xor(p0, 1);
        p0 += __shfl_xor(p0, 2);
        p0 += __shfl_xor(p0, 4);
        p0 += __shfl_xor(p0, 8);
        if (__all(p0 <= m + 8.f)) {
            const float f0 = __expf(p0 - m);
            d += f0; a0 += f0 * x0.x; a1 += f0 * x0.y; a2 += f0 * x0.z; a3 += f0 * x0.w;
        } else {
            const float mn = fmaxf(m, p0);
            const float sc = __expf(m - mn);
            const float f0 = __expf(p0 - mn);
            d  = d  * sc + f0;
            a0 = a0 * sc + f0 * x0.x;
            a1 = a1 * sc + f0 * x0.y;
            a2 = a2 * sc + f0 * x0.z;
            a3 = a3 * sc + f0 * x0.w;
            m = mn;
        }
    }

    const float inv = 1.f / (d + 1e-16f);
    if (MODE == 0) {
        const int c = lane * 4;
        float v[4];
        v[0] = lrelu(a0 * inv + bias[c + 0]);
        v[1] = lrelu(a1 * inv + bias[c + 1]);
        v[2] = lrelu(a2 * inv + bias[c + 2]);
        v[3] = lrelu(a3 * inv + bias[c + 3]);
        ushort4 H, M4;
        unsigned short* pH = &H.x; unsigned short* pM = &M4.x;
#pragma unroll
        for (int j = 0; j < 4; ++j) {
            unsigned short h = f2bf(v[j]);
            pH[j] = h;
            pM[j] = f2bf(v[j] - bf2f(h));
        }
        const size_t o = (size_t)node * 64 + lane;   // ushort4 index
        ((ushort4*)oh)[o] = H;
        ((ushort4*)om)[o] = M4;
    } else {
        float v0 = a0 * inv, v1 = a1 * inv, v2 = a2 * inv, v3 = a3 * inv;
        v0 += __shfl_xor(v0, 16); v0 += __shfl_xor(v0, 32);
        v1 += __shfl_xor(v1, 16); v1 += __shfl_xor(v1, 32);
        v2 += __shfl_xor(v2, 16); v2 += __shfl_xor(v2, 32);
        v3 += __shfl_xor(v3, 16); v3 += __shfl_xor(v3, 32);
        if (lane < 16) {
            const int c = lane * 4;
            float4 o;
            o.x = v0 * 0.25f + bias[c + 0];
            o.y = v1 * 0.25f + bias[c + 1];
            o.z = v2 * 0.25f + bias[c + 2];
            o.w = v3 * 0.25f + bias[c + 3];
            ((float4*)(of + (size_t)node * 64))[lane] = o;
        }
    }
}

// ---------- global max pool (batch is sorted) ----------
#define PNB 32
__global__ __launch_bounds__(64) void k_pool(const float* __restrict__ h3,
                                             const int* __restrict__ batch,
                                             unsigned* gmax) {
    const int lane = threadIdx.x;
    const int start = blockIdx.x * PNB;
    if (start >= NN) return;
    const int end = min(start + PNB, NN);
    int curg = batch[start];
    float best = -INFINITY;
    for (int n = start; n < end; ++n) {
        int g = batch[n];
        if (g != curg) {
            atomicMax(&gmax[curg * 64 + lane], fenc(best));
            best = -INFINITY;
            curg = g;
        }
        best = fmaxf(best, h3[(size_t)n * 64 + lane]);
    }
    atomicMax(&gmax[curg * 64 + lane], fenc(best));
}

__global__ void k_decode(const unsigned* __restrict__ gmax, float* __restrict__ outg) {
    int i = blockIdx.x * blockDim.x + threadIdx.x;
    if (i < GG * 64) outg[i] = fdec(gmax[i]);
}

__global__ __launch_bounds__(128) void k_head(const float* __restrict__ g,
                                              const float* __restrict__ Wc,
                                              const float* __restrict__ bc,
                                              float* __restrict__ logits) {
    const int t = threadIdx.x;
    const int gr = t >> 1, o = t & 1;
    float s = bc[o];
    for (int c = 0; c < 64; ++c) s = fmaf(g[gr * 64 + c], Wc[c * 2 + o], s);
    logits[t] = s;
}

// ---------- launch ----------
extern "C" void kernel_launch(void* const* d_in, const int* in_sizes, int n_in,
                              void* d_out, int out_size, void* d_ws, size_t ws_size,
                              hipStream_t stream) {
    const float* x     = (const float*)d_in[0];
    const int*   ei    = (const int*)d_in[1];
    const int*   batch = (const int*)d_in[2];
    const float* Wl1 = (const float*)d_in[3];
    const float* Wr1 = (const float*)d_in[4];
    const float* att1 = (const float*)d_in[5];
    const float* b1  = (const float*)d_in[6];
    const float* Wl2 = (const float*)d_in[7];
    const float* Wr2 = (const float*)d_in[8];
    const float* att2 = (const float*)d_in[9];
    const float* b2  = (const float*)d_in[10];
    const float* Wl3 = (const float*)d_in[11];
    const float* Wr3 = (const float*)d_in[12];
    const float* att3 = (const float*)d_in[13];
    const float* b3  = (const float*)d_in[14];
    const float* Wc  = (const float*)d_in[15];
    const float* bc  = (const float*)d_in[16];
    float* out = (float*)d_out;   // [0..127]=logits, [128..4223]=g

    char* ws = (char*)d_ws;
    size_t off = 0;
    auto alloc = [&](size_t bytes) -> void* {
        void* p = ws + off;
        off += (bytes + 255) & ~(size_t)255;
        return p;
    };
    float*  xlr = (float*)alloc((size_t)NN * 512 * 4);    // combined xl|xr
    ushort* Ah  = (ushort*)alloc((size_t)NN * 256 * 2);
    ushort* Am  = (ushort*)alloc((size_t)NN * 256 * 2);
    // combined transposed weights per layer: [512][K] bf16, 2 planes
    const int Ksz[3] = {128, 256, 256};
    ushort* wtc[3][2];
    for (int l = 0; l < 3; ++l)
        for (int s = 0; s < 2; ++s)
            wtc[l][s] = (ushort*)alloc((size_t)512 * Ksz[l] * 2);
    int*   deg     = (int*)alloc((size_t)NN * 4);
    int*   cursor  = (int*)alloc((size_t)NN * 4);
    int*   row_ptr = (int*)alloc((size_t)(NN + 1) * 4);
    int*   csr_src = (int*)alloc((size_t)EE * 4);
    unsigned* gmax = (unsigned*)alloc((size_t)GG * 64 * 4);
    float* h3 = (float*)Ah;   // alias: Ah dead once layer-3 GEMM has read it
    if (off > ws_size) return;

    const int* esrc = ei;
    const int* edst = ei + EE;

    // CSR build (graph identical across layers)
    k_init<<<(NN + 255) / 256, 256, 0, stream>>>(deg, gmax);
    k_count<<<(EE + 255) / 256, 256, 0, stream>>>(edst, deg);
    k_scan<<<1, SCAN_T, 0, stream>>>(deg, row_ptr, cursor);
    k_scatter<<<(EE + 255) / 256, 256, 0, stream>>>(esrc, edst, cursor, csr_src);

    // splits
    k_xsplit<<<(NN * 128 / 4 + 255) / 256, 256, 0, stream>>>(x, Ah, Am, NN * 128 / 4);
    const float* Ws[6] = {Wl1, Wr1, Wl2, Wr2, Wl3, Wr3};
    for (int w = 0; w < 6; ++w) {
        const int l = w >> 1, woff = (w & 1) * 256, K = Ksz[l];
        dim3 g(8, K / 32), b(32, 8);
        k_wsplit<<<g, b, 0, stream>>>(Ws[w], K, woff, wtc[l][0], wtc[l][1]);
    }

    const dim3 gg((NN + GBM - 1) / GBM, 4);   // 313 x 4
    const int agg_blocks = NN / 4;

    // Layer 1 (K=128)
    gemm2c<<<gg, 256, 0, stream>>>(Ah, Am, wtc[0][0], wtc[0][1], xlr, NN, 128);
    k_aggregate<0><<<agg_blocks, 256, 0, stream>>>(xlr, att1, b1, row_ptr, csr_src,
                                                   Ah, Am, nullptr);
    // Layer 2 (K=256)
    gemm2c<<<gg, 256, 0, stream>>>(Ah, Am, wtc[1][0], wtc[1][1], xlr, NN, 256);
    k_aggregate<0><<<agg_blocks, 256, 0, stream>>>(xlr, att2, b2, row_ptr, csr_src,
                                                   Ah, Am, nullptr);
    // Layer 3 (K=256), mean over heads
    gemm2c<<<gg, 256, 0, stream>>>(Ah, Am, wtc[2][0], wtc[2][1], xlr, NN, 256);
    k_aggregate<1><<<agg_blocks, 256, 0, stream>>>(xlr, att3, b3, row_ptr, csr_src,
                                                   nullptr, nullptr, h3);

    // Pool + head
    k_pool<<<(NN + PNB - 1) / PNB, 64, 0, stream>>>(h3, batch, gmax);
    k_decode<<<(GG * 64 + 255) / 256, 256, 0, stream>>>(gmax, out + 128);
    k_head<<<1, 128, 0, stream>>>(out + 128, Wc, bc, out);
}

// Round 10
// 677.662 us; speedup vs baseline: 1.4932x; 1.0414x over previous
//
#include <hip/hip_runtime.h>
#include <cstdint>

#define NN 40000
#define EE 640000
#define GG 64

typedef short bf16x8 __attribute__((ext_vector_type(8)));
typedef float f32x4 __attribute__((ext_vector_type(4)));

// ---------- helpers ----------
__device__ __forceinline__ float lrelu(float x) { return x > 0.f ? x : 0.2f * x; }

__device__ __forceinline__ unsigned short f2bf(float f) {
    unsigned u = __float_as_uint(f);
    return (unsigned short)((u + 0x7FFFu + ((u >> 16) & 1u)) >> 16);
}
__device__ __forceinline__ float bf2f(unsigned short h) {
    return __uint_as_float(((unsigned)h) << 16);
}

__device__ __forceinline__ unsigned fenc(float x) {
    unsigned u = __float_as_uint(x);
    return (u & 0x80000000u) ? ~u : (u | 0x80000000u);
}
__device__ __forceinline__ float fdec(unsigned e) {
    unsigned u = (e & 0x80000000u) ? (e ^ 0x80000000u) : ~e;
    return __uint_as_float(u);
}
#define ENC_NEG_INF 0x007FFFFFu

// async global->LDS, 16B per lane (addrspacecast form — verified r7)
__device__ __forceinline__ void gload16(const void* g, void* l) {
    __builtin_amdgcn_global_load_lds(
        (const __attribute__((address_space(1))) unsigned int*)g,
        (__attribute__((address_space(3))) unsigned int*)l,
        16, 0, 0);
}

// ---------- CSR build ----------
__global__ void k_init(int* deg, unsigned* gmax) {
    int i = blockIdx.x * blockDim.x + threadIdx.x;
    if (i < NN) deg[i] = 0;
    if (i < GG * 64) gmax[i] = ENC_NEG_INF;
}

__global__ void k_count(const int* __restrict__ dst, int* deg) {
    int e = blockIdx.x * blockDim.x + threadIdx.x;
    if (e < EE) atomicAdd(&deg[dst[e]], 1);
}

#define SCAN_T 1024
__global__ __launch_bounds__(SCAN_T) void k_scan(const int* __restrict__ deg,
                                                 int* row_ptr, int* cursor) {
    __shared__ int part[SCAN_T];
    const int t = threadIdx.x;
    const int CH = (NN + SCAN_T - 1) / SCAN_T;
    const int base = t * CH;
    int s = 0;
    for (int j = 0; j < CH; ++j) {
        int idx = base + j;
        if (idx < NN) s += deg[idx];
    }
    part[t] = s;
    __syncthreads();
    for (int off = 1; off < SCAN_T; off <<= 1) {
        int v = (t >= off) ? part[t - off] : 0;
        __syncthreads();
        part[t] += v;
        __syncthreads();
    }
    int run = (t == 0) ? 0 : part[t - 1];
    for (int j = 0; j < CH; ++j) {
        int idx = base + j;
        if (idx < NN) {
            row_ptr[idx] = run;
            cursor[idx]  = run;
            run += deg[idx];
        }
    }
    if (t == SCAN_T - 1) row_ptr[NN] = run;
}

__global__ void k_scatter(const int* __restrict__ src, const int* __restrict__ dst,
                          int* cursor, int* csr_src) {
    int e = blockIdx.x * blockDim.x + threadIdx.x;
    if (e < EE) {
        int p = atomicAdd(&cursor[dst[e]], 1);
        csr_src[p] = src[e];
    }
}

// ---------- bf16x2 split of a dense f32 array ----------
__global__ void k_xsplit(const float* __restrict__ x,
                         ushort* __restrict__ ah, ushort* __restrict__ am, int total4) {
    int i = blockIdx.x * blockDim.x + threadIdx.x;
    if (i >= total4) return;
    float4 v = ((const float4*)x)[i];
    ushort4 H, M;
    float* pv = &v.x;
    unsigned short* pH = &H.x; unsigned short* pM = &M.x;
#pragma unroll
    for (int j = 0; j < 4; ++j) {
        float a = pv[j];
        unsigned short h = f2bf(a);
        pH[j] = h;
        pM[j] = f2bf(a - bf2f(h));
    }
    ((ushort4*)ah)[i] = H;
    ((ushort4*)am)[i] = M;
}

// ---------- transpose + bf16x2 split: W[K][256] f32 -> combined Wt{h,m}[512][K] bf16 ----------
__global__ __launch_bounds__(256) void k_wsplit(const float* __restrict__ W, int K, int woff,
                                                ushort* __restrict__ th,
                                                ushort* __restrict__ tm) {
    __shared__ float t[32][33];
    const int n0 = blockIdx.x * 32;
    const int k0 = blockIdx.y * 32;
    const int tx = threadIdx.x;
    const int ty = threadIdx.y;
#pragma unroll
    for (int i = 0; i < 4; ++i) {
        int kl = ty * 4 + i;
        t[kl][tx] = W[(size_t)(k0 + kl) * 256 + n0 + tx];
    }
    __syncthreads();
#pragma unroll
    for (int i = 0; i < 4; ++i) {
        int nl = ty * 4 + i;
        float a = t[tx][nl];
        unsigned short h = f2bf(a);
        size_t o = (size_t)(woff + n0 + nl) * K + k0 + tx;
        th[o] = h;
        tm[o] = f2bf(a - bf2f(h));
    }
}

// ---------- bf16x2-split MFMA GEMM (combined): C[M][512] = A[M][K] @ B[K][512] ----------
// A planes [M][K]; B planes TRANSPOSED [512][K]. 128x128 tile, BK=32, 4 waves
// of 64x64, double-buffered LDS + 2-phase prefetch.
// XCD-aware tile swizzle: hardware assigns consecutive blockIdx round-robin to
// the 8 XCDs; we map b -> t = (b%8)*157 + b/8 so each XCD owns a CONTIGUOUS
// run of tiles t, with bn = t&3 fastest -> the 4 blocks sharing an A-tile run
// on the same XCD and hit its L2 (16 resident A-tiles = 2MB < 4MB L2).
// Products: h*h + h*m + m*h.
#define GBM 128
#define GBK 32
#define NTILE 1252            // 313 bm x 4 bn
#define CHUNK 157             // ceil(1252/8)
__global__ __launch_bounds__(256, 2) void gemm2c(const ushort* __restrict__ Ah,
                                                 const ushort* __restrict__ Am,
                                                 const ushort* __restrict__ Bh,
                                                 const ushort* __restrict__ Bm,
                                                 float* __restrict__ C,
                                                 int M, int K) {
    const int b = blockIdx.x;
    const int t0 = (b & 7) * CHUNK + (b >> 3);
    if (t0 >= NTILE) return;                    // uniform whole-block exit
    const int bm = (t0 >> 2) * GBM;
    const int bn = (t0 & 3) * 128;

    __shared__ ushort sAh[2][GBM * GBK];
    __shared__ ushort sAm[2][GBM * GBK];
    __shared__ ushort sBh[2][GBM * GBK];
    __shared__ ushort sBm[2][GBM * GBK];
    const int tid  = threadIdx.x;
    const int lane = tid & 63;
    const int wv   = tid >> 6;
    const int wm   = wv & 1;
    const int wn   = wv >> 1;

    // wave -> staged tile (uniform selects)
    const ushort* gsrc = (wv == 0) ? Ah : (wv == 1) ? Am : (wv == 2) ? Bh : Bm;
    ushort* l0 = (wv == 0) ? sAh[0] : (wv == 1) ? sAm[0] : (wv == 2) ? sBh[0] : sBm[0];
    ushort* l1 = (wv == 0) ? sAh[1] : (wv == 1) ? sAm[1] : (wv == 2) ? sBh[1] : sBm[1];
    const int rowbase = (wv < 2) ? bm : bn;

    f32x4 acc[4][4];
#pragma unroll
    for (int i = 0; i < 4; ++i)
#pragma unroll
        for (int j = 0; j < 4; ++j)
            acc[i][j] = (f32x4){0.f, 0.f, 0.f, 0.f};

    const int rl = lane >> 2;       // staging row-in-group 0..15
    const int cs = lane & 3;        // staging LDS chunk slot 0..3
    const int fc = lane >> 4;       // fragment k-chunk 0..3
    const int fr = lane & 15;       // fragment row 0..15

    auto stage = [&](ushort* lb, int kt) {
        const int k0 = kt * GBK;
#pragma unroll
        for (int j = 0; j < 8; ++j) {
            const int lrow = j * 16 + rl;
            const int c    = cs ^ ((lrow >> 1) & 3);   // pre-swizzled source chunk
            int grow = rowbase + lrow;
            grow = (grow >= M) ? (M - 1) : grow;       // only A tiles can trigger
            gload16(gsrc + (size_t)grow * K + k0 + c * 8, lb + j * 512);
        }
    };

    stage(l0, 0);
    __syncthreads();                 // vmcnt(0) drain + barrier (prologue tile ready)

    const int nt = K / GBK;
    for (int t = 0; t < nt; ++t) {
        if (t + 1 < nt) stage((t & 1) ? l0 : l1, t + 1);   // issue next-tile loads

        const int bsel = t & 1;
        const ushort* pAh = sAh[bsel];
        const ushort* pAm = sAm[bsel];
        const ushort* pBh = sBh[bsel];
        const ushort* pBm = sBm[bsel];

        bf16x8 aH[4], aM[4], bH[4], bM[4];
#pragma unroll
        for (int mi = 0; mi < 4; ++mi) {
            const int row = wm * 64 + mi * 16 + fr;
            const int idx = row * 32 + (fc ^ ((row >> 1) & 3)) * 8;
            aH[mi] = *(const bf16x8*)&pAh[idx];
            aM[mi] = *(const bf16x8*)&pAm[idx];
        }
#pragma unroll
        for (int ni = 0; ni < 4; ++ni) {
            const int row = wn * 64 + ni * 16 + fr;
            const int idx = row * 32 + (fc ^ ((row >> 1) & 3)) * 8;
            bH[ni] = *(const bf16x8*)&pBh[idx];
            bM[ni] = *(const bf16x8*)&pBm[idx];
        }

#pragma unroll
        for (int mi = 0; mi < 4; ++mi)
#pragma unroll
            for (int ni = 0; ni < 4; ++ni) {
                f32x4 c0 = acc[mi][ni];
                c0 = __builtin_amdgcn_mfma_f32_16x16x32_bf16(aH[mi], bH[ni], c0, 0, 0, 0);
                c0 = __builtin_amdgcn_mfma_f32_16x16x32_bf16(aH[mi], bM[ni], c0, 0, 0, 0);
                c0 = __builtin_amdgcn_mfma_f32_16x16x32_bf16(aM[mi], bH[ni], c0, 0, 0, 0);
                acc[mi][ni] = c0;
            }
        __syncthreads();   // drains next-tile loads (hidden under compute) + barrier
    }

    // epilogue: C/D layout col=lane&15, row=(lane>>4)*4+reg ; C stride 512
#pragma unroll
    for (int mi = 0; mi < 4; ++mi) {
#pragma unroll
        for (int r = 0; r < 4; ++r) {
            const int row = bm + wm * 64 + mi * 16 + (lane >> 4) * 4 + r;
            if (row < M) {
#pragma unroll
                for (int ni = 0; ni < 4; ++ni) {
                    const int col = bn + wn * 64 + ni * 16 + (lane & 15);
                    C[(size_t)row * 512 + col] = acc[mi][ni][r];
                }
            }
        }
    }
}

// ---------- fused GATv2 edge-softmax aggregation ----------
// xlr[M][512]: cols 0..255 = xl (source transform), 256..511 = xr (target).
// One wave per node; lane l owns flat channels 4l..4l+3 (head = l>>4).
// 4-edge unroll + defer-max (THR=8).
// MODE 0: concat 4 heads + bias + LeakyReLU, bf16x2-split output
// MODE 1: mean over 4 heads (64 out) + bias, f32 output
template <int MODE>
__global__ __launch_bounds__(256) void k_aggregate(const float* __restrict__ xlr,
                                                   const float* __restrict__ att,
                                                   const float* __restrict__ bias,
                                                   const int* __restrict__ row_ptr,
                                                   const int* __restrict__ csr_src,
                                                   ushort* __restrict__ oh,
                                                   ushort* __restrict__ om,
                                                   float* __restrict__ of) {
    const int wave = threadIdx.x >> 6;
    const int lane = threadIdx.x & 63;
    const int node = blockIdx.x * 4 + wave;
    if (node >= NN) return;

    const float4 xri = ((const float4*)(xlr + (size_t)node * 512 + 256))[lane];
    const float4 av  = ((const float4*)att)[lane];

    float m = -INFINITY, d = 0.f;
    float a0 = 0.f, a1 = 0.f, a2 = 0.f, a3 = 0.f;

    const int start = row_ptr[node];
    const int endp  = row_ptr[node + 1];
    const int L = endp - start + 1;   // + self-loop as last virtual edge

    int i = 0;
    for (; i + 4 <= L; i += 4) {
        const int e0 = start + i;
        const int s0 = (e0     < endp) ? csr_src[e0]     : node;
        const int s1 = (e0 + 1 < endp) ? csr_src[e0 + 1] : node;
        const int s2 = (e0 + 2 < endp) ? csr_src[e0 + 2] : node;
        const int s3 = (e0 + 3 < endp) ? csr_src[e0 + 3] : node;
        const float4 x0 = ((const float4*)(xlr + (size_t)s0 * 512))[lane];
        const float4 x1 = ((const float4*)(xlr + (size_t)s1 * 512))[lane];
        const float4 x2 = ((const float4*)(xlr + (size_t)s2 * 512))[lane];
        const float4 x3 = ((const float4*)(xlr + (size_t)s3 * 512))[lane];
        float p0 = av.x * lrelu(x0.x + xri.x) + av.y * lrelu(x0.y + xri.y)
                 + av.z * lrelu(x0.z + xri.z) + av.w * lrelu(x0.w + xri.w);
        float p1 = av.x * lrelu(x1.x + xri.x) + av.y * lrelu(x1.y + xri.y)
                 + av.z * lrelu(x1.z + xri.z) + av.w * lrelu(x1.w + xri.w);
        float p2 = av.x * lrelu(x2.x + xri.x) + av.y * lrelu(x2.y + xri.y)
                 + av.z * lrelu(x2.z + xri.z) + av.w * lrelu(x2.w + xri.w);
        float p3 = av.x * lrelu(x3.x + xri.x) + av.y * lrelu(x3.y + xri.y)
                 + av.z * lrelu(x3.z + xri.z) + av.w * lrelu(x3.w + xri.w);
        p0 += __shfl_xor(p0, 1); p1 += __shfl_xor(p1, 1);
        p2 += __shfl_xor(p2, 1); p3 += __shfl_xor(p3, 1);
        p0 += __shfl_xor(p0, 2); p1 += __shfl_xor(p1, 2);
        p2 += __shfl_xor(p2, 2); p3 += __shfl_xor(p3, 2);
        p0 += __shfl_xor(p0, 4); p1 += __shfl_xor(p1, 4);
        p2 += __shfl_xor(p2, 4); p3 += __shfl_xor(p3, 4);
        p0 += __shfl_xor(p0, 8); p1 += __shfl_xor(p1, 8);
        p2 += __shfl_xor(p2, 8); p3 += __shfl_xor(p3, 8);

        const float pm = fmaxf(fmaxf(p0, p1), fmaxf(p2, p3));
        if (__all(pm <= m + 8.f)) {      // defer-max fast path
            const float f0 = __expf(p0 - m), f1 = __expf(p1 - m);
            const float f2 = __expf(p2 - m), f3 = __expf(p3 - m);
            d  += f0 + f1 + f2 + f3;
            a0 += f0 * x0.x + f1 * x1.x + f2 * x2.x + f3 * x3.x;
            a1 += f0 * x0.y + f1 * x1.y + f2 * x2.y + f3 * x3.y;
            a2 += f0 * x0.z + f1 * x1.z + f2 * x2.z + f3 * x3.z;
            a3 += f0 * x0.w + f1 * x1.w + f2 * x2.w + f3 * x3.w;
        } else {
            const float mn = fmaxf(m, pm);
            const float sc = __expf(m - mn);   // m=-inf first iter -> 0
            const float f0 = __expf(p0 - mn), f1 = __expf(p1 - mn);
            const float f2 = __expf(p2 - mn), f3 = __expf(p3 - mn);
            d  = d  * sc + f0 + f1 + f2 + f3;
            a0 = a0 * sc + f0 * x0.x + f1 * x1.x + f2 * x2.x + f3 * x3.x;
            a1 = a1 * sc + f0 * x0.y + f1 * x1.y + f2 * x2.y + f3 * x3.y;
            a2 = a2 * sc + f0 * x0.z + f1 * x1.z + f2 * x2.z + f3 * x3.z;
            a3 = a3 * sc + f0 * x0.w + f1 * x1.w + f2 * x2.w + f3 * x3.w;
            m = mn;
        }
    }
    for (; i < L; ++i) {   // tail (1..3 edges incl. self-loop)
        const int e0 = start + i;
        const int s0 = (e0 < endp) ? csr_src[e0] : node;
        const float4 x0 = ((const float4*)(xlr + (size_t)s0 * 512))[lane];
        float p0 = av.x * lrelu(x0.x + xri.x) + av.y * lrelu(x0.y + xri.y)
                 + av.z * lrelu(x0.z + xri.z) + av.w * lrelu(x0.w + xri.w);
        p0 += __shfl_xor(p0, 1);
        p0 += __shfl_xor(p0, 2);
        p0 += __shfl_xor(p0, 4);
        p0 += __shfl_xor(p0, 8);
        if (__all(p0 <= m + 8.f)) {
            const float f0 = __expf(p0 - m);
            d += f0; a0 += f0 * x0.x; a1 += f0 * x0.y; a2 += f0 * x0.z; a3 += f0 * x0.w;
        } else {
            const float mn = fmaxf(m, p0);
            const float sc = __expf(m - mn);
            const float f0 = __expf(p0 - mn);
            d  = d  * sc + f0;
            a0 = a0 * sc + f0 * x0.x;
            a1 = a1 * sc + f0 * x0.y;
            a2 = a2 * sc + f0 * x0.z;
            a3 = a3 * sc + f0 * x0.w;
            m = mn;
        }
    }

    const float inv = 1.f / (d + 1e-16f);
    if (MODE == 0) {
        const int c = lane * 4;
        float v[4];
        v[0] = lrelu(a0 * inv + bias[c + 0]);
        v[1] = lrelu(a1 * inv + bias[c + 1]);
        v[2] = lrelu(a2 * inv + bias[c + 2]);
        v[3] = lrelu(a3 * inv + bias[c + 3]);
        ushort4 H, M4;
        unsigned short* pH = &H.x; unsigned short* pM = &M4.x;
#pragma unroll
        for (int j = 0; j < 4; ++j) {
            unsigned short h = f2bf(v[j]);
            pH[j] = h;
            pM[j] = f2bf(v[j] - bf2f(h));
        }
        const size_t o = (size_t)node * 64 + lane;   // ushort4 index
        ((ushort4*)oh)[o] = H;
        ((ushort4*)om)[o] = M4;
    } else {
        float v0 = a0 * inv, v1 = a1 * inv, v2 = a2 * inv, v3 = a3 * inv;
        v0 += __shfl_xor(v0, 16); v0 += __shfl_xor(v0, 32);
        v1 += __shfl_xor(v1, 16); v1 += __shfl_xor(v1, 32);
        v2 += __shfl_xor(v2, 16); v2 += __shfl_xor(v2, 32);
        v3 += __shfl_xor(v3, 16); v3 += __shfl_xor(v3, 32);
        if (lane < 16) {
            const int c = lane * 4;
            float4 o;
            o.x = v0 * 0.25f + bias[c + 0];
            o.y = v1 * 0.25f + bias[c + 1];
            o.z = v2 * 0.25f + bias[c + 2];
            o.w = v3 * 0.25f + bias[c + 3];
            ((float4*)(of + (size_t)node * 64))[lane] = o;
        }
    }
}

// ---------- global max pool (batch is sorted) ----------
#define PNB 32
__global__ __launch_bounds__(64) void k_pool(const float* __restrict__ h3,
                                             const int* __restrict__ batch,
                                             unsigned* gmax) {
    const int lane = threadIdx.x;
    const int start = blockIdx.x * PNB;
    if (start >= NN) return;
    const int end = min(start + PNB, NN);
    int curg = batch[start];
    float best = -INFINITY;
    for (int n = start; n < end; ++n) {
        int g = batch[n];
        if (g != curg) {
            atomicMax(&gmax[curg * 64 + lane], fenc(best));
            best = -INFINITY;
            curg = g;
        }
        best = fmaxf(best, h3[(size_t)n * 64 + lane]);
    }
    atomicMax(&gmax[curg * 64 + lane], fenc(best));
}

__global__ void k_decode(const unsigned* __restrict__ gmax, float* __restrict__ outg) {
    int i = blockIdx.x * blockDim.x + threadIdx.x;
    if (i < GG * 64) outg[i] = fdec(gmax[i]);
}

__global__ __launch_bounds__(128) void k_head(const float* __restrict__ g,
                                              const float* __restrict__ Wc,
                                              const float* __restrict__ bc,
                                              float* __restrict__ logits) {
    const int t = threadIdx.x;
    const int gr = t >> 1, o = t & 1;
    float s = bc[o];
    for (int c = 0; c < 64; ++c) s = fmaf(g[gr * 64 + c], Wc[c * 2 + o], s);
    logits[t] = s;
}

// ---------- launch ----------
extern "C" void kernel_launch(void* const* d_in, const int* in_sizes, int n_in,
                              void* d_out, int out_size, void* d_ws, size_t ws_size,
                              hipStream_t stream) {
    const float* x     = (const float*)d_in[0];
    const int*   ei    = (const int*)d_in[1];
    const int*   batch = (const int*)d_in[2];
    const float* Wl1 = (const float*)d_in[3];
    const float* Wr1 = (const float*)d_in[4];
    const float* att1 = (const float*)d_in[5];
    const float* b1  = (const float*)d_in[6];
    const float* Wl2 = (const float*)d_in[7];
    const float* Wr2 = (const float*)d_in[8];
    const float* att2 = (const float*)d_in[9];
    const float* b2  = (const float*)d_in[10];
    const float* Wl3 = (const float*)d_in[11];
    const float* Wr3 = (const float*)d_in[12];
    const float* att3 = (const float*)d_in[13];
    const float* b3  = (const float*)d_in[14];
    const float* Wc  = (const float*)d_in[15];
    const float* bc  = (const float*)d_in[16];
    float* out = (float*)d_out;   // [0..127]=logits, [128..4223]=g

    char* ws = (char*)d_ws;
    size_t off = 0;
    auto alloc = [&](size_t bytes) -> void* {
        void* p = ws + off;
        off += (bytes + 255) & ~(size_t)255;
        return p;
    };
    float*  xlr = (float*)alloc((size_t)NN * 512 * 4);    // combined xl|xr
    ushort* Ah  = (ushort*)alloc((size_t)NN * 256 * 2);
    ushort* Am  = (ushort*)alloc((size_t)NN * 256 * 2);
    // combined transposed weights per layer: [512][K] bf16, 2 planes
    const int Ksz[3] = {128, 256, 256};
    ushort* wtc[3][2];
    for (int l = 0; l < 3; ++l)
        for (int s = 0; s < 2; ++s)
            wtc[l][s] = (ushort*)alloc((size_t)512 * Ksz[l] * 2);
    int*   deg     = (int*)alloc((size_t)NN * 4);
    int*   cursor  = (int*)alloc((size_t)NN * 4);
    int*   row_ptr = (int*)alloc((size_t)(NN + 1) * 4);
    int*   csr_src = (int*)alloc((size_t)EE * 4);
    unsigned* gmax = (unsigned*)alloc((size_t)GG * 64 * 4);
    float* h3 = (float*)Ah;   // alias: Ah dead once layer-3 GEMM has read it
    if (off > ws_size) return;

    const int* esrc = ei;
    const int* edst = ei + EE;

    // CSR build (graph identical across layers)
    k_init<<<(NN + 255) / 256, 256, 0, stream>>>(deg, gmax);
    k_count<<<(EE + 255) / 256, 256, 0, stream>>>(edst, deg);
    k_scan<<<1, SCAN_T, 0, stream>>>(deg, row_ptr, cursor);
    k_scatter<<<(EE + 255) / 256, 256, 0, stream>>>(esrc, edst, cursor, csr_src);

    // splits
    k_xsplit<<<(NN * 128 / 4 + 255) / 256, 256, 0, stream>>>(x, Ah, Am, NN * 128 / 4);
    const float* Ws[6] = {Wl1, Wr1, Wl2, Wr2, Wl3, Wr3};
    for (int w = 0; w < 6; ++w) {
        const int l = w >> 1, woff = (w & 1) * 256, K = Ksz[l];
        dim3 g(8, K / 32), b(32, 8);
        k_wsplit<<<g, b, 0, stream>>>(Ws[w], K, woff, wtc[l][0], wtc[l][1]);
    }

    const int gemm_blocks = 8 * CHUNK;        // 1256 (XCD-swizzled tile space)
    const int agg_blocks = NN / 4;

    // Layer 1 (K=128)
    gemm2c<<<gemm_blocks, 256, 0, stream>>>(Ah, Am, wtc[0][0], wtc[0][1], xlr, NN, 128);
    k_aggregate<0><<<agg_blocks, 256, 0, stream>>>(xlr, att1, b1, row_ptr, csr_src,
                                                   Ah, Am, nullptr);
    // Layer 2 (K=256)
    gemm2c<<<gemm_blocks, 256, 0, stream>>>(Ah, Am, wtc[1][0], wtc[1][1], xlr, NN, 256);
    k_aggregate<0><<<agg_blocks, 256, 0, stream>>>(xlr, att2, b2, row_ptr, csr_src,
                                                   Ah, Am, nullptr);
    // Layer 3 (K=256), mean over heads
    gemm2c<<<gemm_blocks, 256, 0, stream>>>(Ah, Am, wtc[2][0], wtc[2][1], xlr, NN, 256);
    k_aggregate<1><<<agg_blocks, 256, 0, stream>>>(xlr, att3, b3, row_ptr, csr_src,
                                                   nullptr, nullptr, h3);

    // Pool + head
    k_pool<<<(NN + PNB - 1) / PNB, 64, 0, stream>>>(h3, batch, gmax);
    k_decode<<<(GG * 64 + 255) / 256, 256, 0, stream>>>(gmax, out + 128);
    k_head<<<1, 128, 0, stream>>>(out + 128, Wc, bc, out);
}